// Round 1
// baseline (4109.741 us; speedup 1.0000x reference)
//
#include <hip/hip_runtime.h>
#include <math.h>

#define NPIX 196608
#define NW   12288   // NPIX / 16

__device__ __forceinline__ float gelu_exact(float x) {
    return 0.5f * x * (1.0f + erff(x * 0.70710678118654752f));
}

// ---------------- ff1: h = gelu(x @ w_ff1 + b_ff1), x[N,64] -> h[N,128] ---
__global__ __launch_bounds__(256) void k_ff1(
    const float* __restrict__ x, const float* __restrict__ w,
    const float* __restrict__ b, float* __restrict__ h)
{
    __shared__ float xs[16 * 64];
    const int tid = threadIdx.x;
    const int base = blockIdx.x * 16;
    for (int i = tid; i < 1024; i += 256) xs[i] = x[base * 64 + i];
    __syncthreads();
    const int col  = tid & 127;
    const int half = tid >> 7;   // 0/1 -> rows 0..7 / 8..15
    float acc[8];
    const float bv = b[col];
#pragma unroll
    for (int r = 0; r < 8; ++r) acc[r] = bv;
    const float4* xs4 = reinterpret_cast<const float4*>(xs);
    for (int k4 = 0; k4 < 16; ++k4) {
        const int k = k4 * 4;
        const float w0 = w[(k + 0) * 128 + col];
        const float w1 = w[(k + 1) * 128 + col];
        const float w2 = w[(k + 2) * 128 + col];
        const float w3 = w[(k + 3) * 128 + col];
#pragma unroll
        for (int r = 0; r < 8; ++r) {
            float4 xv = xs4[(half * 8 + r) * 16 + k4];
            acc[r] += xv.x * w0 + xv.y * w1 + xv.z * w2 + xv.w * w3;
        }
    }
#pragma unroll
    for (int r = 0; r < 8; ++r)
        h[(base + half * 8 + r) * 128 + col] = gelu_exact(acc[r]);
}

// ------------- attention block: h += proj(attn(ln1(h))) per 16-token window
// OFFSET = 0 (block 0) or 8 (block 1, cyclic shift folded into indexing)
template <int OFFSET>
__global__ __launch_bounds__(256) void k_attn(
    float* __restrict__ h,
    const float* __restrict__ g, const float* __restrict__ be,
    const float* __restrict__ wq, const float* __restrict__ bq,
    const float* __restrict__ wp, const float* __restrict__ bp)
{
    __shared__ float hs[16 * 128];
    __shared__ float xn[16 * 128];     // ln output, later reused for attn-out
    __shared__ float qkv[3][16 * 128];
    __shared__ float sc[4 * 16 * 16];
    const int tid  = threadIdx.x;
    const int tok0 = blockIdx.x * 16 + OFFSET;

    for (int i = tid; i < 2048; i += 256) {
        int row = i >> 7, c = i & 127;
        int t = tok0 + row; if (t >= NPIX) t -= NPIX;
        hs[i] = h[t * 128 + c];
    }
    __syncthreads();

    // ---- LayerNorm: 16 threads per row
    {
        const int r = tid >> 4, l = tid & 15;
        float s = 0.f;
#pragma unroll
        for (int k = 0; k < 8; ++k) s += hs[r * 128 + l + 16 * k];
#pragma unroll
        for (int m = 8; m >= 1; m >>= 1) s += __shfl_xor(s, m, 64);
        const float mu = s * (1.0f / 128.0f);
        float v = 0.f;
#pragma unroll
        for (int k = 0; k < 8; ++k) {
            float d = hs[r * 128 + l + 16 * k] - mu; v += d * d;
        }
#pragma unroll
        for (int m = 8; m >= 1; m >>= 1) v += __shfl_xor(v, m, 64);
        const float rstd = rsqrtf(v * (1.0f / 128.0f) + 1e-5f);
#pragma unroll
        for (int k = 0; k < 8; ++k) {
            int c = l + 16 * k;
            xn[r * 128 + c] = (hs[r * 128 + c] - mu) * rstd * g[c] + be[c];
        }
    }
    __syncthreads();

    // ---- qkv = xn @ wq + bq   (16x128 @ 128x384)
    {
        const float4* xn4 = reinterpret_cast<const float4*>(xn);
        for (int col = tid; col < 384; col += 256) {
            float acc[16];
            const float bv = bq[col];
#pragma unroll
            for (int r = 0; r < 16; ++r) acc[r] = bv;
            for (int k4 = 0; k4 < 32; ++k4) {
                const int k = k4 * 4;
                const float w0 = wq[(k + 0) * 384 + col];
                const float w1 = wq[(k + 1) * 384 + col];
                const float w2 = wq[(k + 2) * 384 + col];
                const float w3 = wq[(k + 3) * 384 + col];
#pragma unroll
                for (int r = 0; r < 16; ++r) {
                    float4 xv = xn4[r * 32 + k4];
                    acc[r] += xv.x * w0 + xv.y * w1 + xv.z * w2 + xv.w * w3;
                }
            }
            const int sel = col >> 7, cc = col & 127;
#pragma unroll
            for (int r = 0; r < 16; ++r) qkv[sel][r * 128 + cc] = acc[r];
        }
    }
    __syncthreads();

    // ---- scores = q·k * D^-1/2  (4 heads, 16x16)
    {
        const float4* q4 = reinterpret_cast<const float4*>(qkv[0]);
        const float4* k4 = reinterpret_cast<const float4*>(qkv[1]);
        for (int e = tid; e < 1024; e += 256) {
            const int hh = e >> 8, q_ = (e >> 4) & 15, k_ = e & 15;
            float acc = 0.f;
#pragma unroll
            for (int d4 = 0; d4 < 8; ++d4) {
                float4 qv = q4[q_ * 32 + hh * 8 + d4];
                float4 kv = k4[k_ * 32 + hh * 8 + d4];
                acc += qv.x * kv.x + qv.y * kv.y + qv.z * kv.z + qv.w * kv.w;
            }
            sc[e] = acc * 0.17677669529663687f;
        }
    }
    __syncthreads();

    // ---- softmax over keys: 64 rows of 16
    if (tid < 64) {
        float* row = sc + tid * 16;
        float mx = row[0];
#pragma unroll
        for (int k = 1; k < 16; ++k) mx = fmaxf(mx, row[k]);
        float sum = 0.f;
#pragma unroll
        for (int k = 0; k < 16; ++k) { float e = expf(row[k] - mx); row[k] = e; sum += e; }
        const float inv = 1.0f / sum;
#pragma unroll
        for (int k = 0; k < 16; ++k) row[k] *= inv;
    }
    __syncthreads();

    // ---- attn @ v -> xn (reuse)
    for (int e = tid; e < 2048; e += 256) {
        const int row = e >> 7, c = e & 127, hh = c >> 5;
        float acc = 0.f;
#pragma unroll
        for (int k = 0; k < 16; ++k)
            acc += sc[hh * 256 + row * 16 + k] * qkv[2][k * 128 + c];
        xn[e] = acc;
    }
    __syncthreads();

    // ---- proj + residual: h = hs + xn @ wp + bp
    {
        const int col = tid & 127, half = tid >> 7;
        float acc[8];
        const float bv = bp[col];
#pragma unroll
        for (int r = 0; r < 8; ++r) acc[r] = bv;
        const float4* a4 = reinterpret_cast<const float4*>(xn);
        for (int k4 = 0; k4 < 32; ++k4) {
            const int k = k4 * 4;
            const float w0 = wp[(k + 0) * 128 + col];
            const float w1 = wp[(k + 1) * 128 + col];
            const float w2 = wp[(k + 2) * 128 + col];
            const float w3 = wp[(k + 3) * 128 + col];
#pragma unroll
            for (int r = 0; r < 8; ++r) {
                float4 xv = a4[(half * 8 + r) * 32 + k4];
                acc[r] += xv.x * w0 + xv.y * w1 + xv.z * w2 + xv.w * w3;
            }
        }
#pragma unroll
        for (int r = 0; r < 8; ++r) {
            const int row = half * 8 + r;
            int t = tok0 + row; if (t >= NPIX) t -= NPIX;
            h[t * 128 + col] = hs[row * 128 + col] + acc[r];
        }
    }
}

// ------------- MLP block: h += mlp2(gelu(mlp1(ln2(h))))
__global__ __launch_bounds__(256) void k_mlp(
    float* __restrict__ h,
    const float* __restrict__ g, const float* __restrict__ be,
    const float* __restrict__ w1, const float* __restrict__ b1,
    const float* __restrict__ w2, const float* __restrict__ b2)
{
    __shared__ float hs[16 * 128];
    __shared__ float xn[16 * 128];
    __shared__ float u[16 * 512];
    const int tid  = threadIdx.x;
    const int base = blockIdx.x * 16;

    for (int i = tid; i < 2048; i += 256) hs[i] = h[base * 128 + i];
    __syncthreads();

    // ---- LayerNorm (ln2)
    {
        const int r = tid >> 4, l = tid & 15;
        float s = 0.f;
#pragma unroll
        for (int k = 0; k < 8; ++k) s += hs[r * 128 + l + 16 * k];
#pragma unroll
        for (int m = 8; m >= 1; m >>= 1) s += __shfl_xor(s, m, 64);
        const float mu = s * (1.0f / 128.0f);
        float v = 0.f;
#pragma unroll
        for (int k = 0; k < 8; ++k) {
            float d = hs[r * 128 + l + 16 * k] - mu; v += d * d;
        }
#pragma unroll
        for (int m = 8; m >= 1; m >>= 1) v += __shfl_xor(v, m, 64);
        const float rstd = rsqrtf(v * (1.0f / 128.0f) + 1e-5f);
#pragma unroll
        for (int k = 0; k < 8; ++k) {
            int c = l + 16 * k;
            xn[r * 128 + c] = (hs[r * 128 + c] - mu) * rstd * g[c] + be[c];
        }
    }
    __syncthreads();

    // ---- u = gelu(xn @ w1 + b1)   (16x128 @ 128x512)
    {
        const float4* xn4 = reinterpret_cast<const float4*>(xn);
        for (int col = tid; col < 512; col += 256) {
            float acc[16];
            const float bv = b1[col];
#pragma unroll
            for (int r = 0; r < 16; ++r) acc[r] = bv;
            for (int k4 = 0; k4 < 32; ++k4) {
                const int k = k4 * 4;
                const float w0 = w1[(k + 0) * 512 + col];
                const float w1v = w1[(k + 1) * 512 + col];
                const float w2v = w1[(k + 2) * 512 + col];
                const float w3v = w1[(k + 3) * 512 + col];
#pragma unroll
                for (int r = 0; r < 16; ++r) {
                    float4 xv = xn4[r * 32 + k4];
                    acc[r] += xv.x * w0 + xv.y * w1v + xv.z * w2v + xv.w * w3v;
                }
            }
#pragma unroll
            for (int r = 0; r < 16; ++r) u[r * 512 + col] = gelu_exact(acc[r]);
        }
    }
    __syncthreads();

    // ---- h = hs + u @ w2 + b2    (16x512 @ 512x128)
    {
        const int col = tid & 127, half = tid >> 7;
        float acc[8];
        const float bv = b2[col];
#pragma unroll
        for (int r = 0; r < 8; ++r) acc[r] = bv;
        const float4* u4 = reinterpret_cast<const float4*>(u);
        for (int k4 = 0; k4 < 128; ++k4) {
            const int k = k4 * 4;
            const float w0 = w2[(k + 0) * 128 + col];
            const float w1v = w2[(k + 1) * 128 + col];
            const float w2v = w2[(k + 2) * 128 + col];
            const float w3v = w2[(k + 3) * 128 + col];
#pragma unroll
            for (int r = 0; r < 8; ++r) {
                float4 uv = u4[(half * 8 + r) * 128 + k4];
                acc[r] += uv.x * w0 + uv.y * w1v + uv.z * w2v + uv.w * w3v;
            }
        }
#pragma unroll
        for (int r = 0; r < 8; ++r)
            h[(base + half * 8 + r) * 128 + col] =
                hs[(half * 8 + r) * 128 + col] + acc[r];
    }
}

// ------------- ff2: out = x + h @ w_ff2 + b_ff2   (h[N,128] -> [N,64])
__global__ __launch_bounds__(256) void k_ff2(
    const float* __restrict__ x, const float* __restrict__ h,
    const float* __restrict__ w, const float* __restrict__ b,
    float* __restrict__ out)
{
    __shared__ float hs[16 * 128];
    const int tid  = threadIdx.x;
    const int base = blockIdx.x * 16;
    for (int i = tid; i < 2048; i += 256) hs[i] = h[base * 128 + i];
    __syncthreads();
    const int col = tid & 63, q = tid >> 6;  // q: 0..3 -> rows q*4..q*4+3
    float acc[4];
    const float bv = b[col];
#pragma unroll
    for (int r = 0; r < 4; ++r) acc[r] = bv;
    const float4* hs4 = reinterpret_cast<const float4*>(hs);
    for (int k4 = 0; k4 < 32; ++k4) {
        const int k = k4 * 4;
        const float w0 = w[(k + 0) * 64 + col];
        const float w1 = w[(k + 1) * 64 + col];
        const float w2 = w[(k + 2) * 64 + col];
        const float w3 = w[(k + 3) * 64 + col];
#pragma unroll
        for (int r = 0; r < 4; ++r) {
            float4 hv = hs4[(q * 4 + r) * 32 + k4];
            acc[r] += hv.x * w0 + hv.y * w1 + hv.z * w2 + hv.w * w3;
        }
    }
#pragma unroll
    for (int r = 0; r < 4; ++r) {
        const int row = q * 4 + r;
        out[(base + row) * 64 + col] = x[(base + row) * 64 + col] + acc[r];
    }
}

extern "C" void kernel_launch(void* const* d_in, const int* in_sizes, int n_in,
                              void* d_out, int out_size, void* d_ws, size_t ws_size,
                              hipStream_t stream) {
    (void)in_sizes; (void)n_in; (void)out_size; (void)ws_size;
    const float* x      = (const float*)d_in[0];
    const float* w_ff1  = (const float*)d_in[1];
    const float* b_ff1  = (const float*)d_in[2];
    const float* ln1_g  = (const float*)d_in[3];
    const float* ln1_b  = (const float*)d_in[4];
    const float* w_qkv  = (const float*)d_in[5];
    const float* b_qkv  = (const float*)d_in[6];
    const float* w_proj = (const float*)d_in[7];
    const float* b_proj = (const float*)d_in[8];
    const float* ln2_g  = (const float*)d_in[9];
    const float* ln2_b  = (const float*)d_in[10];
    const float* w_mlp1 = (const float*)d_in[11];
    const float* b_mlp1 = (const float*)d_in[12];
    const float* w_mlp2 = (const float*)d_in[13];
    const float* b_mlp2 = (const float*)d_in[14];
    const float* w_ff2  = (const float*)d_in[15];
    const float* b_ff2  = (const float*)d_in[16];
    float* out = (float*)d_out;
    float* h   = (float*)d_ws;   // [NPIX, 128] fp32 = 100.7 MB

    dim3 blk(256);
    k_ff1<<<NW, blk, 0, stream>>>(x, w_ff1, b_ff1, h);

    // block 0 (no shift)
    k_attn<0><<<NW, blk, 0, stream>>>(h, ln1_g, ln1_b, w_qkv, b_qkv, w_proj, b_proj);
    k_mlp<<<NW, blk, 0, stream>>>(h, ln2_g, ln2_b, w_mlp1, b_mlp1, w_mlp2, b_mlp2);

    // block 1 (shift = 8, folded into window indexing)
    k_attn<8><<<NW, blk, 0, stream>>>(h, ln1_g + 128, ln1_b + 128,
                                      w_qkv + 49152, b_qkv + 384,
                                      w_proj + 16384, b_proj + 128);
    k_mlp<<<NW, blk, 0, stream>>>(h, ln2_g + 128, ln2_b + 128,
                                  w_mlp1 + 65536, b_mlp1 + 512,
                                  w_mlp2 + 65536, b_mlp2 + 128);

    k_ff2<<<NW, blk, 0, stream>>>(x, h, w_ff2, b_ff2, out);
}

// Round 2
// 894.101 us; speedup vs baseline: 4.5965x; 4.5965x over previous
//
#include <hip/hip_runtime.h>
#include <hip/hip_bf16.h>
#include <math.h>

#define NPIX 196608
#define SCALE_Q 0.17677669529663687f

typedef __attribute__((ext_vector_type(4))) float f32x4;
typedef __attribute__((ext_vector_type(8))) short short8;

__device__ __forceinline__ float gelu_f(float x) {
    // tanh-form GELU: x * sigmoid(2*0.7978845608*(x + 0.044715 x^3)); |err| < 1e-3 abs
    float yy = 1.5957691216057308f * (x + 0.044715f * x * x * x);
    float e = __expf(yy);
    return x - x * __builtin_amdgcn_rcpf(e + 1.0f);
}

__device__ __forceinline__ void lds_fence() {
    asm volatile("s_waitcnt lgkmcnt(0)" ::: "memory");
    __builtin_amdgcn_sched_barrier(0);
}

__device__ __forceinline__ short8 lds8(const __hip_bfloat16* p) {
    return *reinterpret_cast<const short8*>(p);
}

// ---------------- weight convert+transpose to bf16: dst[n*K+k] = src[k*N+n]
__global__ __launch_bounds__(256) void k_convert(
    const float* __restrict__ wff1, const float* __restrict__ wqkv,
    const float* __restrict__ wproj, const float* __restrict__ wmlp1,
    const float* __restrict__ wmlp2, const float* __restrict__ wff2,
    __hip_bfloat16* __restrict__ dst)
{
    int gid = blockIdx.x * 256 + threadIdx.x;
    if (gid < 8192) {                       // ff1t [128][64] <- [64][128]
        int n = gid >> 6, k = gid & 63;
        dst[gid] = __float2bfloat16(wff1[k * 128 + n]);
    } else if (gid < 106496) {              // qkvt 2x[384][128] <- [128][384]
        int r = gid - 8192; int l = r / 49152; r -= l * 49152;
        int n = r >> 7, k = r & 127;
        dst[gid] = __float2bfloat16(wqkv[l * 49152 + k * 384 + n]);
    } else if (gid < 139264) {              // projt 2x[128][128]
        int r = gid - 106496; int l = r / 16384; r -= l * 16384;
        int n = r >> 7, k = r & 127;
        dst[gid] = __float2bfloat16(wproj[l * 16384 + k * 128 + n]);
    } else if (gid < 270336) {              // mlp1t 2x[512][128] <- [128][512]
        int r = gid - 139264; int l = r / 65536; r -= l * 65536;
        int n = r >> 7, k = r & 127;
        dst[gid] = __float2bfloat16(wmlp1[l * 65536 + k * 512 + n]);
    } else if (gid < 401408) {              // mlp2t 2x[128][512] <- [512][128]
        int r = gid - 270336; int l = r / 65536; r -= l * 65536;
        int n = r >> 9, k = r & 511;
        dst[gid] = __float2bfloat16(wmlp2[l * 65536 + k * 128 + n]);
    } else if (gid < 409600) {              // ff2t [64][128] <- [128][64]
        int r = gid - 401408;
        int n = r >> 7, k = r & 127;
        dst[gid] = __float2bfloat16(wff2[k * 64 + n]);
    }
}

// ---------------- ff1: h = gelu(x @ w_ff1 + b), [N,64] -> [N,128], M-tile 64
__global__ __launch_bounds__(256) void k_ff1(
    const float* __restrict__ x, const __hip_bfloat16* __restrict__ wt,
    const float* __restrict__ b, float* __restrict__ h)
{
    __shared__ __align__(16) __hip_bfloat16 xs[64][72];
    __shared__ __align__(16) __hip_bfloat16 wb[128][72];
    const int tid = threadIdx.x, base = blockIdx.x * 64;
    const int wid = tid >> 6, lane = tid & 63, lrow = lane & 15, lgrp = lane >> 4;

    for (int e4 = tid; e4 < 1024; e4 += 256) {
        int row = e4 >> 4, c4 = (e4 & 15) * 4;
        float4 v = reinterpret_cast<const float4*>(x + (size_t)(base + row) * 64)[e4 & 15];
        xs[row][c4 + 0] = __float2bfloat16(v.x);
        xs[row][c4 + 1] = __float2bfloat16(v.y);
        xs[row][c4 + 2] = __float2bfloat16(v.z);
        xs[row][c4 + 3] = __float2bfloat16(v.w);
    }
    for (int c = tid; c < 1024; c += 256) {
        int row = c >> 3, k8 = (c & 7) * 8;
        *reinterpret_cast<int4*>(&wb[row][k8]) =
            *reinterpret_cast<const int4*>(wt + row * 64 + k8);
    }
    __syncthreads();

    short8 a[2];
#pragma unroll
    for (int kk = 0; kk < 2; ++kk)
        a[kk] = lds8(&xs[wid * 16 + lrow][kk * 32 + lgrp * 8]);
#pragma unroll
    for (int nt = 0; nt < 8; ++nt) {
        f32x4 c = {0.f, 0.f, 0.f, 0.f};
#pragma unroll
        for (int kk = 0; kk < 2; ++kk) {
            short8 bv = lds8(&wb[nt * 16 + lrow][kk * 32 + lgrp * 8]);
            c = __builtin_amdgcn_mfma_f32_16x16x32_bf16(a[kk], bv, c, 0, 0, 0);
        }
        int col = nt * 16 + lrow;
        float bb = b[col];
#pragma unroll
        for (int i = 0; i < 4; ++i)
            h[(size_t)(base + wid * 16 + lgrp * 4 + i) * 128 + col] = gelu_f(c[i] + bb);
    }
}

// ---------------- attention block (MFMA). OFFSET folds the cyclic shift.
template <int OFFSET>
__global__ __launch_bounds__(256) void k_attn(
    float* __restrict__ h,
    const float* __restrict__ g, const float* __restrict__ be,
    const __hip_bfloat16* __restrict__ wqt, const float* __restrict__ bq,
    const __hip_bfloat16* __restrict__ wpt, const float* __restrict__ bp)
{
    __shared__ __align__(16) __hip_bfloat16 xn[64][136];   // ln out, reused for attn-out
    __shared__ __align__(16) __hip_bfloat16 qk[64][264];   // q (scaled) cols 0..127, k 128..255
    __shared__ __align__(16) __hip_bfloat16 vt[4][128][40];// per wave: [vcol][key], key>=16 zero
    __shared__ __align__(16) __hip_bfloat16 pl[4][64][40]; // per wave: [head*16+q][key], key>=16 zero
    __shared__ __align__(16) __hip_bfloat16 wb[128][136];
    const int tid = threadIdx.x, base = blockIdx.x * 64;
    const int wid = tid >> 6, lane = tid & 63, lrow = lane & 15, lgrp = lane >> 4;

    {   // zero vt, pl (padding keys must be 0)
        int* vz = reinterpret_cast<int*>(&vt[0][0][0]);
        for (int i = tid; i < 10240; i += 256) vz[i] = 0;
        int* pz = reinterpret_cast<int*>(&pl[0][0][0]);
        for (int i = tid; i < 5120; i += 256) pz[i] = 0;
    }
    {   // LayerNorm on shifted tokens -> xn bf16
        const int r = tid >> 2, c0 = (tid & 3) * 32;
        int t = base + OFFSET + r; if (t >= NPIX) t -= NPIX;
        const float* hp = h + (size_t)t * 128 + c0;
        float v[32];
#pragma unroll
        for (int i = 0; i < 8; ++i) {
            float4 t4 = reinterpret_cast<const float4*>(hp)[i];
            v[4*i+0] = t4.x; v[4*i+1] = t4.y; v[4*i+2] = t4.z; v[4*i+3] = t4.w;
        }
        float s = 0.f;
#pragma unroll
        for (int i = 0; i < 32; ++i) s += v[i];
        s += __shfl_xor(s, 1, 64); s += __shfl_xor(s, 2, 64);
        float mu = s * (1.f / 128.f);
        float var = 0.f;
#pragma unroll
        for (int i = 0; i < 32; ++i) { float d = v[i] - mu; var += d * d; }
        var += __shfl_xor(var, 1, 64); var += __shfl_xor(var, 2, 64);
        float rstd = rsqrtf(var * (1.f / 128.f) + 1e-5f);
#pragma unroll
        for (int i = 0; i < 32; ++i)
            xn[r][c0 + i] = __float2bfloat16((v[i] - mu) * rstd * g[c0 + i] + be[c0 + i]);
    }
    __syncthreads();

    // ---- qkv GEMM, N in 3 chunks of 128
    for (int nc = 0; nc < 3; ++nc) {
        for (int c = tid; c < 2048; c += 256) {
            int row = c >> 4, k8 = (c & 15) * 8;
            *reinterpret_cast<int4*>(&wb[row][k8]) =
                *reinterpret_cast<const int4*>(wqt + (size_t)(nc * 128 + row) * 128 + k8);
        }
        __syncthreads();
        short8 a[4];
#pragma unroll
        for (int kk = 0; kk < 4; ++kk)
            a[kk] = lds8(&xn[wid * 16 + lrow][kk * 32 + lgrp * 8]);
#pragma unroll
        for (int nt = 0; nt < 8; ++nt) {
            f32x4 c = {0.f, 0.f, 0.f, 0.f};
#pragma unroll
            for (int kk = 0; kk < 4; ++kk) {
                short8 bvv = lds8(&wb[nt * 16 + lrow][kk * 32 + lgrp * 8]);
                c = __builtin_amdgcn_mfma_f32_16x16x32_bf16(a[kk], bvv, c, 0, 0, 0);
            }
            int col = nc * 128 + nt * 16 + lrow;
            float bb = bq[col];
            if (col < 128) {
#pragma unroll
                for (int i = 0; i < 4; ++i)
                    qk[wid * 16 + lgrp * 4 + i][col] = __float2bfloat16((c[i] + bb) * SCALE_Q);
            } else if (col < 256) {
#pragma unroll
                for (int i = 0; i < 4; ++i)
                    qk[wid * 16 + lgrp * 4 + i][col] = __float2bfloat16(c[i] + bb);
            } else {
#pragma unroll
                for (int i = 0; i < 4; ++i)
                    vt[wid][col - 256][lgrp * 4 + i] = __float2bfloat16(c[i] + bb);
            }
        }
        __syncthreads();
    }

    // ---- per-wave: scores (1 MFMA/head), softmax, PV (2 MFMA/head)
    f32x4 ao[8];
#pragma unroll
    for (int hh = 0; hh < 4; ++hh) {
        short8 aq = lds8(&qk[wid * 16 + lrow][hh * 32 + lgrp * 8]);
        short8 bk = lds8(&qk[wid * 16 + lrow][128 + hh * 32 + lgrp * 8]);
        f32x4 z = {0.f, 0.f, 0.f, 0.f};
        f32x4 s = __builtin_amdgcn_mfma_f32_16x16x32_bf16(aq, bk, z, 0, 0, 0);
#pragma unroll
        for (int i = 0; i < 4; ++i) {
            float m_ = s[i];
            m_ = fmaxf(m_, __shfl_xor(m_, 1, 64));
            m_ = fmaxf(m_, __shfl_xor(m_, 2, 64));
            m_ = fmaxf(m_, __shfl_xor(m_, 4, 64));
            m_ = fmaxf(m_, __shfl_xor(m_, 8, 64));
            float e = __expf(s[i] - m_);
            float sum = e;
            sum += __shfl_xor(sum, 1, 64);
            sum += __shfl_xor(sum, 2, 64);
            sum += __shfl_xor(sum, 4, 64);
            sum += __shfl_xor(sum, 8, 64);
            pl[wid][hh * 16 + lgrp * 4 + i][lrow] =
                __float2bfloat16(e * __builtin_amdgcn_rcpf(sum));
        }
    }
    lds_fence();
#pragma unroll
    for (int hh = 0; hh < 4; ++hh) {
        short8 ap = lds8(&pl[wid][hh * 16 + lrow][lgrp * 8]);
#pragma unroll
        for (int t2 = 0; t2 < 2; ++t2) {
            short8 bvv = lds8(&vt[wid][hh * 32 + t2 * 16 + lrow][lgrp * 8]);
            f32x4 z = {0.f, 0.f, 0.f, 0.f};
            ao[hh * 2 + t2] = __builtin_amdgcn_mfma_f32_16x16x32_bf16(ap, bvv, z, 0, 0, 0);
        }
    }
    // attn-out -> xn (reuse; all xn reads finished before last qkv barrier)
#pragma unroll
    for (int nt = 0; nt < 8; ++nt)
#pragma unroll
        for (int i = 0; i < 4; ++i)
            xn[wid * 16 + lgrp * 4 + i][nt * 16 + lrow] = __float2bfloat16(ao[nt][i]);
    __syncthreads();

    // ---- proj GEMM + residual
    for (int c = tid; c < 2048; c += 256) {
        int row = c >> 4, k8 = (c & 15) * 8;
        *reinterpret_cast<int4*>(&wb[row][k8]) =
            *reinterpret_cast<const int4*>(wpt + (size_t)row * 128 + k8);
    }
    __syncthreads();
    short8 a[4];
#pragma unroll
    for (int kk = 0; kk < 4; ++kk)
        a[kk] = lds8(&xn[wid * 16 + lrow][kk * 32 + lgrp * 8]);
#pragma unroll
    for (int nt = 0; nt < 8; ++nt) {
        f32x4 c = {0.f, 0.f, 0.f, 0.f};
#pragma unroll
        for (int kk = 0; kk < 4; ++kk) {
            short8 bvv = lds8(&wb[nt * 16 + lrow][kk * 32 + lgrp * 8]);
            c = __builtin_amdgcn_mfma_f32_16x16x32_bf16(a[kk], bvv, c, 0, 0, 0);
        }
        int col = nt * 16 + lrow;
        float bb = bp[col];
#pragma unroll
        for (int i = 0; i < 4; ++i) {
            int row = wid * 16 + lgrp * 4 + i;
            int t = base + OFFSET + row; if (t >= NPIX) t -= NPIX;
            size_t idx = (size_t)t * 128 + col;
            h[idx] = h[idx] + bb + c[i];
        }
    }
}

// ---------------- MLP block: h += mlp2(gelu(mlp1(ln2(h)))), M-tile 64
__global__ __launch_bounds__(256) void k_mlp(
    float* __restrict__ h,
    const float* __restrict__ g, const float* __restrict__ be,
    const __hip_bfloat16* __restrict__ w1t, const float* __restrict__ b1,
    const __hip_bfloat16* __restrict__ w2t, const float* __restrict__ b2)
{
    __shared__ __align__(16) __hip_bfloat16 xn[64][136];
    __shared__ __align__(16) __hip_bfloat16 wb[128][136];
    __shared__ __align__(16) __hip_bfloat16 u[64][520];
    const int tid = threadIdx.x, base = blockIdx.x * 64;
    const int wid = tid >> 6, lane = tid & 63, lrow = lane & 15, lgrp = lane >> 4;

    {   // LayerNorm -> xn
        const int r = tid >> 2, c0 = (tid & 3) * 32;
        const float* hp = h + (size_t)(base + r) * 128 + c0;
        float v[32];
#pragma unroll
        for (int i = 0; i < 8; ++i) {
            float4 t4 = reinterpret_cast<const float4*>(hp)[i];
            v[4*i+0] = t4.x; v[4*i+1] = t4.y; v[4*i+2] = t4.z; v[4*i+3] = t4.w;
        }
        float s = 0.f;
#pragma unroll
        for (int i = 0; i < 32; ++i) s += v[i];
        s += __shfl_xor(s, 1, 64); s += __shfl_xor(s, 2, 64);
        float mu = s * (1.f / 128.f);
        float var = 0.f;
#pragma unroll
        for (int i = 0; i < 32; ++i) { float d = v[i] - mu; var += d * d; }
        var += __shfl_xor(var, 1, 64); var += __shfl_xor(var, 2, 64);
        float rstd = rsqrtf(var * (1.f / 128.f) + 1e-5f);
#pragma unroll
        for (int i = 0; i < 32; ++i)
            xn[r][c0 + i] = __float2bfloat16((v[i] - mu) * rstd * g[c0 + i] + be[c0 + i]);
    }
    __syncthreads();

    // ---- mlp1: u = gelu(xn @ w1 + b1), N in 4 chunks of 128
    for (int nc = 0; nc < 4; ++nc) {
        for (int c = tid; c < 2048; c += 256) {
            int row = c >> 4, k8 = (c & 15) * 8;
            *reinterpret_cast<int4*>(&wb[row][k8]) =
                *reinterpret_cast<const int4*>(w1t + (size_t)(nc * 128 + row) * 128 + k8);
        }
        __syncthreads();
        short8 a[4];
#pragma unroll
        for (int kk = 0; kk < 4; ++kk)
            a[kk] = lds8(&xn[wid * 16 + lrow][kk * 32 + lgrp * 8]);
#pragma unroll
        for (int nt = 0; nt < 8; ++nt) {
            f32x4 c = {0.f, 0.f, 0.f, 0.f};
#pragma unroll
            for (int kk = 0; kk < 4; ++kk) {
                short8 bvv = lds8(&wb[nt * 16 + lrow][kk * 32 + lgrp * 8]);
                c = __builtin_amdgcn_mfma_f32_16x16x32_bf16(a[kk], bvv, c, 0, 0, 0);
            }
            float bb = b1[nc * 128 + nt * 16 + lrow];
#pragma unroll
            for (int i = 0; i < 4; ++i)
                u[wid * 16 + lgrp * 4 + i][nc * 128 + nt * 16 + lrow] =
                    __float2bfloat16(gelu_f(c[i] + bb));
        }
        __syncthreads();
    }

    // ---- mlp2: acc += u @ w2, K in 4 chunks of 128
    f32x4 acc[8];
#pragma unroll
    for (int nt = 0; nt < 8; ++nt) acc[nt] = (f32x4){0.f, 0.f, 0.f, 0.f};
    for (int kc = 0; kc < 4; ++kc) {
        for (int c = tid; c < 2048; c += 256) {
            int row = c >> 4, k8 = (c & 15) * 8;
            *reinterpret_cast<int4*>(&wb[row][k8]) =
                *reinterpret_cast<const int4*>(w2t + (size_t)row * 512 + kc * 128 + k8);
        }
        __syncthreads();
        short8 a[4];
#pragma unroll
        for (int kk = 0; kk < 4; ++kk)
            a[kk] = lds8(&u[wid * 16 + lrow][kc * 128 + kk * 32 + lgrp * 8]);
#pragma unroll
        for (int nt = 0; nt < 8; ++nt)
#pragma unroll
            for (int kk = 0; kk < 4; ++kk) {
                short8 bvv = lds8(&wb[nt * 16 + lrow][kk * 32 + lgrp * 8]);
                acc[nt] = __builtin_amdgcn_mfma_f32_16x16x32_bf16(a[kk], bvv, acc[nt], 0, 0, 0);
            }
        __syncthreads();
    }
#pragma unroll
    for (int nt = 0; nt < 8; ++nt) {
        int col = nt * 16 + lrow;
        float bb = b2[col];
#pragma unroll
        for (int i = 0; i < 4; ++i) {
            size_t idx = (size_t)(base + wid * 16 + lgrp * 4 + i) * 128 + col;
            h[idx] = h[idx] + bb + acc[nt][i];
        }
    }
}

// ---------------- ff2: out = x + h @ w_ff2 + b
__global__ __launch_bounds__(256) void k_ff2(
    const float* __restrict__ x, const float* __restrict__ h,
    const __hip_bfloat16* __restrict__ wt, const float* __restrict__ b,
    float* __restrict__ out)
{
    __shared__ __align__(16) __hip_bfloat16 hsb[64][136];
    __shared__ __align__(16) __hip_bfloat16 wb[64][136];
    const int tid = threadIdx.x, base = blockIdx.x * 64;
    const int wid = tid >> 6, lane = tid & 63, lrow = lane & 15, lgrp = lane >> 4;

    for (int e4 = tid; e4 < 2048; e4 += 256) {
        int row = e4 >> 5, c4 = (e4 & 31) * 4;
        float4 v = reinterpret_cast<const float4*>(h + (size_t)(base + row) * 128)[e4 & 31];
        hsb[row][c4 + 0] = __float2bfloat16(v.x);
        hsb[row][c4 + 1] = __float2bfloat16(v.y);
        hsb[row][c4 + 2] = __float2bfloat16(v.z);
        hsb[row][c4 + 3] = __float2bfloat16(v.w);
    }
    for (int c = tid; c < 1024; c += 256) {
        int row = c >> 4, k8 = (c & 15) * 8;
        *reinterpret_cast<int4*>(&wb[row][k8]) =
            *reinterpret_cast<const int4*>(wt + (size_t)row * 128 + k8);
    }
    __syncthreads();

    short8 a[4];
#pragma unroll
    for (int kk = 0; kk < 4; ++kk)
        a[kk] = lds8(&hsb[wid * 16 + lrow][kk * 32 + lgrp * 8]);
#pragma unroll
    for (int nt = 0; nt < 4; ++nt) {
        f32x4 c = {0.f, 0.f, 0.f, 0.f};
#pragma unroll
        for (int kk = 0; kk < 4; ++kk) {
            short8 bvv = lds8(&wb[nt * 16 + lrow][kk * 32 + lgrp * 8]);
            c = __builtin_amdgcn_mfma_f32_16x16x32_bf16(a[kk], bvv, c, 0, 0, 0);
        }
        int col = nt * 16 + lrow;
        float bb = b[col];
#pragma unroll
        for (int i = 0; i < 4; ++i) {
            size_t gidx = (size_t)(base + wid * 16 + lgrp * 4 + i) * 64 + col;
            out[gidx] = x[gidx] + bb + c[i];
        }
    }
}

extern "C" void kernel_launch(void* const* d_in, const int* in_sizes, int n_in,
                              void* d_out, int out_size, void* d_ws, size_t ws_size,
                              hipStream_t stream) {
    (void)in_sizes; (void)n_in; (void)out_size; (void)ws_size;
    const float* x      = (const float*)d_in[0];
    const float* w_ff1  = (const float*)d_in[1];
    const float* b_ff1  = (const float*)d_in[2];
    const float* ln1_g  = (const float*)d_in[3];
    const float* ln1_b  = (const float*)d_in[4];
    const float* w_qkv  = (const float*)d_in[5];
    const float* b_qkv  = (const float*)d_in[6];
    const float* w_proj = (const float*)d_in[7];
    const float* b_proj = (const float*)d_in[8];
    const float* ln2_g  = (const float*)d_in[9];
    const float* ln2_b  = (const float*)d_in[10];
    const float* w_mlp1 = (const float*)d_in[11];
    const float* b_mlp1 = (const float*)d_in[12];
    const float* w_mlp2 = (const float*)d_in[13];
    const float* b_mlp2 = (const float*)d_in[14];
    const float* w_ff2  = (const float*)d_in[15];
    const float* b_ff2  = (const float*)d_in[16];
    float* out = (float*)d_out;

    float* h = (float*)d_ws;                                   // [NPIX,128] fp32
    __hip_bfloat16* wbf = (__hip_bfloat16*)((char*)d_ws + (size_t)NPIX * 128 * 4);
    __hip_bfloat16* ff1t  = wbf;            // [128][64]
    __hip_bfloat16* qkvt  = wbf + 8192;     // 2x[384][128]
    __hip_bfloat16* projt = wbf + 106496;   // 2x[128][128]
    __hip_bfloat16* mlp1t = wbf + 139264;   // 2x[512][128]
    __hip_bfloat16* mlp2t = wbf + 270336;   // 2x[128][512]
    __hip_bfloat16* ff2t  = wbf + 401408;   // [64][128]

    dim3 blk(256);
    k_convert<<<1600, blk, 0, stream>>>(w_ff1, w_qkv, w_proj, w_mlp1, w_mlp2, w_ff2, wbf);

    const int NB = NPIX / 64;  // 3072
    k_ff1<<<NB, blk, 0, stream>>>(x, ff1t, b_ff1, h);

    k_attn<0><<<NB, blk, 0, stream>>>(h, ln1_g, ln1_b, qkvt, b_qkv, projt, b_proj);
    k_mlp<<<NB, blk, 0, stream>>>(h, ln2_g, ln2_b, mlp1t, b_mlp1, mlp2t, b_mlp2);

    k_attn<8><<<NB, blk, 0, stream>>>(h, ln1_g + 128, ln1_b + 128,
                                      qkvt + 49152, b_qkv + 384,
                                      projt + 16384, b_proj + 128);
    k_mlp<<<NB, blk, 0, stream>>>(h, ln2_g + 128, ln2_b + 128,
                                  mlp1t + 65536, b_mlp1 + 512,
                                  mlp2t + 65536, b_mlp2 + 128);

    k_ff2<<<NB, blk, 0, stream>>>(x, h, ff2t, b_ff2, out);
}

// Round 3
// 534.826 us; speedup vs baseline: 7.6843x; 1.6718x over previous
//
#include <hip/hip_runtime.h>
#include <hip/hip_bf16.h>
#include <math.h>

#define NPIX 196608
#define SCALE_Q 0.17677669529663687f

typedef __attribute__((ext_vector_type(4))) float f32x4;
typedef __attribute__((ext_vector_type(8))) short short8;
typedef __hip_bfloat16 bf16;

__device__ __forceinline__ float gelu_f(float x) {
    float yy = 1.5957691216057308f * (x + 0.044715f * x * x * x);
    float e = __expf(yy);
    return x - x * __builtin_amdgcn_rcpf(e + 1.0f);
}

__device__ __forceinline__ void lds_fence() {
    asm volatile("s_waitcnt lgkmcnt(0)" ::: "memory");
    __builtin_amdgcn_sched_barrier(0);
}

__device__ __forceinline__ int swz(int row, int el) { return el ^ ((row & 7) << 3); }

__device__ __forceinline__ short bfbits(float f) {
    bf16 h = __float2bfloat16(f);
    return *reinterpret_cast<short*>(&h);
}

// read a 16B MFMA fragment from a swizzled [rows][128] bf16 tile
__device__ __forceinline__ short8 ldsA(const bf16* buf, int row, int el) {
    return *reinterpret_cast<const short8*>(buf + row * 128 + swz(row, el));
}
// global 16B bf16 fragment load
__device__ __forceinline__ short8 gld8(const bf16* p) {
    return *reinterpret_cast<const short8*>(p);
}

// stage 64 rows x 128 cols of bf16 weights into swizzled wb tile
__device__ __forceinline__ void stage_w(const bf16* __restrict__ src, int ldk,
                                        bf16* __restrict__ wb, int tid) {
    int row = tid >> 2, q = tid & 3;
#pragma unroll
    for (int s = 0; s < 4; ++s) {
        int g = q + s * 4;  // 8-el (16B) group 0..15
        int4 v = *reinterpret_cast<const int4*>(src + (size_t)row * ldk + g * 8);
        *reinterpret_cast<int4*>(wb + row * 128 + swz(row, g * 8)) = v;
    }
}

// ---------------- weight convert+transpose to bf16: dst[n*K+k] = src[k*N+n]
__global__ __launch_bounds__(256) void k_convert(
    const float* __restrict__ wff1, const float* __restrict__ wqkv,
    const float* __restrict__ wproj, const float* __restrict__ wmlp1,
    const float* __restrict__ wmlp2, const float* __restrict__ wff2,
    bf16* __restrict__ dst)
{
    int gid = blockIdx.x * 256 + threadIdx.x;
    if (gid < 8192) {                       // ff1t [128][64]
        int n = gid >> 6, k = gid & 63;
        dst[gid] = __float2bfloat16(wff1[k * 128 + n]);
    } else if (gid < 106496) {              // qkvt 2x[384][128]
        int r = gid - 8192; int l = r / 49152; r -= l * 49152;
        int n = r >> 7, k = r & 127;
        dst[gid] = __float2bfloat16(wqkv[l * 49152 + k * 384 + n]);
    } else if (gid < 139264) {              // projt 2x[128][128]
        int r = gid - 106496; int l = r / 16384; r -= l * 16384;
        int n = r >> 7, k = r & 127;
        dst[gid] = __float2bfloat16(wproj[l * 16384 + k * 128 + n]);
    } else if (gid < 270336) {              // mlp1t 2x[512][128]
        int r = gid - 139264; int l = r / 65536; r -= l * 65536;
        int n = r >> 7, k = r & 127;
        dst[gid] = __float2bfloat16(wmlp1[l * 65536 + k * 512 + n]);
    } else if (gid < 401408) {              // mlp2t 2x[128][512]
        int r = gid - 270336; int l = r / 65536; r -= l * 65536;
        int n = r >> 9, k = r & 511;
        dst[gid] = __float2bfloat16(wmlp2[l * 65536 + k * 128 + n]);
    } else if (gid < 409600) {              // ff2t [64][128]
        int r = gid - 401408;
        int n = r >> 7, k = r & 127;
        dst[gid] = __float2bfloat16(wff2[k * 64 + n]);
    }
}

// ---------------- ff1: h = gelu(x @ w_ff1 + b), [N,64] -> [N,128]
__global__ __launch_bounds__(256, 4) void k_ff1(
    const float* __restrict__ x, const bf16* __restrict__ wt,
    const float* __restrict__ b, float* __restrict__ h)
{
    __shared__ bf16 xs[64 * 64];
    __shared__ bf16 wb[128 * 64];
    const int tid = threadIdx.x, base = blockIdx.x * 64;
    const int wid = tid >> 6, lane = tid & 63, lrow = lane & 15, lgrp = lane >> 4;

    {   // x -> xs (bf16, swizzled): 4 thr/row, 2 groups of 8 each
        int row = tid >> 2, q = tid & 3;
#pragma unroll
        for (int s = 0; s < 2; ++s) {
            int g = q + s * 4;
            const float4* src = reinterpret_cast<const float4*>(x + (size_t)(base + row) * 64 + g * 8);
            float4 v0 = src[0], v1 = src[1];
            short8 w;
            w[0] = bfbits(v0.x); w[1] = bfbits(v0.y); w[2] = bfbits(v0.z); w[3] = bfbits(v0.w);
            w[4] = bfbits(v1.x); w[5] = bfbits(v1.y); w[6] = bfbits(v1.z); w[7] = bfbits(v1.w);
            *reinterpret_cast<short8*>(&xs[row * 64 + swz(row, g * 8)]) = w;
        }
    }
    {   // wt stage: 128 rows x 64 el
        int row = tid >> 1, q = tid & 1;
#pragma unroll
        for (int s = 0; s < 4; ++s) {
            int g = q + s * 2;
            int4 v = *reinterpret_cast<const int4*>(wt + row * 64 + g * 8);
            *reinterpret_cast<int4*>(&wb[row * 64 + swz(row, g * 8)]) = v;
        }
    }
    __syncthreads();

    short8 a[2];
#pragma unroll
    for (int kk = 0; kk < 2; ++kk) {
        int r = wid * 16 + lrow;
        a[kk] = *reinterpret_cast<const short8*>(&xs[r * 64 + swz(r, kk * 32 + lgrp * 8)]);
    }
#pragma unroll
    for (int nt = 0; nt < 8; ++nt) {
        f32x4 c = {0.f, 0.f, 0.f, 0.f};
#pragma unroll
        for (int kk = 0; kk < 2; ++kk) {
            int r = nt * 16 + lrow;
            short8 bv = *reinterpret_cast<const short8*>(&wb[r * 64 + swz(r, kk * 32 + lgrp * 8)]);
            c = __builtin_amdgcn_mfma_f32_16x16x32_bf16(a[kk], bv, c, 0, 0, 0);
        }
        int col = nt * 16 + lrow;
        float bb = b[col];
#pragma unroll
        for (int i = 0; i < 4; ++i)
            h[(size_t)(base + wid * 16 + lgrp * 4 + i) * 128 + col] = gelu_f(c[i] + bb);
    }
}

// ---------------- attention block. OFFSET folds the cyclic shift.
template <int OFFSET>
__global__ __launch_bounds__(256, 3) void k_attn(
    float* __restrict__ h,
    const float* __restrict__ g, const float* __restrict__ be,
    const bf16* __restrict__ wqt, const float* __restrict__ bq,
    const bf16* __restrict__ wpt, const float* __restrict__ bp)
{
    __shared__ bf16 bufA[8192];   // xn -> q(scaled) -> attn-out
    __shared__ bf16 bufB[8192];   // k ; P overlays first 4096 after scores
    __shared__ bf16 vt[8192];     // [win][128 d][16 key]
    const int tid = threadIdx.x, base = blockIdx.x * 64;
    const int wid = tid >> 6, lane = tid & 63, lrow = lane & 15, lgrp = lane >> 4;

    {   // LayerNorm (shifted tokens) -> bufA
        const int r = tid >> 2, c0 = (tid & 3) * 32;
        int t = base + OFFSET + r; if (t >= NPIX) t -= NPIX;
        const float* hp = h + (size_t)t * 128 + c0;
        float v[32];
#pragma unroll
        for (int i = 0; i < 8; ++i) {
            float4 t4 = reinterpret_cast<const float4*>(hp)[i];
            v[4*i+0] = t4.x; v[4*i+1] = t4.y; v[4*i+2] = t4.z; v[4*i+3] = t4.w;
        }
        float s = 0.f;
#pragma unroll
        for (int i = 0; i < 32; ++i) s += v[i];
        s += __shfl_xor(s, 1, 64); s += __shfl_xor(s, 2, 64);
        float mu = s * (1.f / 128.f);
        float var = 0.f;
#pragma unroll
        for (int i = 0; i < 32; ++i) { float d = v[i] - mu; var += d * d; }
        var += __shfl_xor(var, 1, 64); var += __shfl_xor(var, 2, 64);
        float rstd = rsqrtf(var * (1.f / 128.f) + 1e-5f);
#pragma unroll
        for (int gph = 0; gph < 4; ++gph) {
            short8 w;
#pragma unroll
            for (int j = 0; j < 8; ++j) {
                int c = c0 + gph * 8 + j;
                w[j] = bfbits((v[gph * 8 + j] - mu) * rstd * g[c] + be[c]);
            }
            *reinterpret_cast<short8*>(&bufA[r * 128 + swz(r, c0 + gph * 8)]) = w;
        }
    }
    __syncthreads();

    // hoist A-fragments (all 64 rows) to registers
    short8 a[4][4];
#pragma unroll
    for (int mt = 0; mt < 4; ++mt)
#pragma unroll
        for (int kk = 0; kk < 4; ++kk)
            a[mt][kk] = ldsA(bufA, mt * 16 + lrow, kk * 32 + lgrp * 8);
    lds_fence();
    __syncthreads();   // all waves done reading bufA

    // ---- qkv GEMM, N-split: wave owns cols [wid*96, wid*96+96)
    const int col0 = wid * 96;
#pragma unroll
    for (int nt = 0; nt < 6; ++nt) {
        int coln = col0 + nt * 16 + lrow;
        float bb = bq[coln];
        short8 b[4];
#pragma unroll
        for (int kk = 0; kk < 4; ++kk)
            b[kk] = gld8(wqt + (size_t)coln * 128 + kk * 32 + lgrp * 8);
#pragma unroll
        for (int mt = 0; mt < 4; ++mt) {
            f32x4 c = {0.f, 0.f, 0.f, 0.f};
#pragma unroll
            for (int kk = 0; kk < 4; ++kk)
                c = __builtin_amdgcn_mfma_f32_16x16x32_bf16(a[mt][kk], b[kk], c, 0, 0, 0);
            if (coln < 128) {
#pragma unroll
                for (int i = 0; i < 4; ++i) {
                    int row = mt * 16 + lgrp * 4 + i;
                    bufA[row * 128 + swz(row, coln)] = __float2bfloat16((c[i] + bb) * SCALE_Q);
                }
            } else if (coln < 256) {
#pragma unroll
                for (int i = 0; i < 4; ++i) {
                    int row = mt * 16 + lgrp * 4 + i;
                    bufB[row * 128 + swz(row, coln - 128)] = __float2bfloat16(c[i] + bb);
                }
            } else {
                int d = coln - 256;
#pragma unroll
                for (int i = 0; i < 4; ++i)
                    vt[mt * 2048 + d * 16 + lgrp * 4 + i] = __float2bfloat16(c[i] + bb);
            }
        }
    }
    __syncthreads();

    // ---- scores + softmax (own window per wave); P kept in registers
    float p[4][4];
#pragma unroll
    for (int hh = 0; hh < 4; ++hh) {
        short8 aq = ldsA(bufA, wid * 16 + lrow, hh * 32 + lgrp * 8);
        short8 bk = ldsA(bufB, wid * 16 + lrow, hh * 32 + lgrp * 8);
        f32x4 z = {0.f, 0.f, 0.f, 0.f};
        f32x4 s = __builtin_amdgcn_mfma_f32_16x16x32_bf16(aq, bk, z, 0, 0, 0);
#pragma unroll
        for (int i = 0; i < 4; ++i) {
            float m_ = s[i];
            m_ = fmaxf(m_, __shfl_xor(m_, 1, 64));
            m_ = fmaxf(m_, __shfl_xor(m_, 2, 64));
            m_ = fmaxf(m_, __shfl_xor(m_, 4, 64));
            m_ = fmaxf(m_, __shfl_xor(m_, 8, 64));
            float e = __expf(s[i] - m_);
            float sum = e;
            sum += __shfl_xor(sum, 1, 64);
            sum += __shfl_xor(sum, 2, 64);
            sum += __shfl_xor(sum, 4, 64);
            sum += __shfl_xor(sum, 8, 64);
            p[hh][i] = e * __builtin_amdgcn_rcpf(sum);
        }
    }
    __syncthreads();   // all scores done -> bufA/bufB reusable

    // P -> bufB (overlay): [wave][h*16+q][16 key]
#pragma unroll
    for (int hh = 0; hh < 4; ++hh)
#pragma unroll
        for (int i = 0; i < 4; ++i)
            bufB[wid * 1024 + (hh * 16 + lgrp * 4 + i) * 16 + lrow] = __float2bfloat16(p[hh][i]);
    lds_fence();

    // ---- PV: out[q][d], K=32 with keys 16..31 zero via zero registers
    short8 zero8 = {0, 0, 0, 0, 0, 0, 0, 0};
#pragma unroll
    for (int hh = 0; hh < 4; ++hh) {
        short8 ap = zero8;
        if (lgrp < 2)
            ap = *reinterpret_cast<const short8*>(&bufB[wid * 1024 + (hh * 16 + lrow) * 16 + lgrp * 8]);
#pragma unroll
        for (int t2 = 0; t2 < 2; ++t2) {
            short8 bv = zero8;
            if (lgrp < 2)
                bv = *reinterpret_cast<const short8*>(&vt[wid * 2048 + (hh * 32 + t2 * 16 + lrow) * 16 + lgrp * 8]);
            f32x4 z = {0.f, 0.f, 0.f, 0.f};
            f32x4 o = __builtin_amdgcn_mfma_f32_16x16x32_bf16(ap, bv, z, 0, 0, 0);
            int coln = hh * 32 + t2 * 16 + lrow;
#pragma unroll
            for (int i = 0; i < 4; ++i) {
                int row = wid * 16 + lgrp * 4 + i;
                bufA[row * 128 + swz(row, coln)] = __float2bfloat16(o[i]);
            }
        }
    }
    __syncthreads();   // attn-out complete

    // ---- proj (N-split: wave owns 32 cols) + residual
    short8 a2[4][4];
#pragma unroll
    for (int mt = 0; mt < 4; ++mt)
#pragma unroll
        for (int kk = 0; kk < 4; ++kk)
            a2[mt][kk] = ldsA(bufA, mt * 16 + lrow, kk * 32 + lgrp * 8);
    const int pc0 = wid * 32;
#pragma unroll
    for (int nt = 0; nt < 2; ++nt) {
        int coln = pc0 + nt * 16 + lrow;
        float bb = bp[coln];
        short8 b[4];
#pragma unroll
        for (int kk = 0; kk < 4; ++kk)
            b[kk] = gld8(wpt + (size_t)coln * 128 + kk * 32 + lgrp * 8);
#pragma unroll
        for (int mt = 0; mt < 4; ++mt) {
            f32x4 c = {0.f, 0.f, 0.f, 0.f};
#pragma unroll
            for (int kk = 0; kk < 4; ++kk)
                c = __builtin_amdgcn_mfma_f32_16x16x32_bf16(a2[mt][kk], b[kk], c, 0, 0, 0);
#pragma unroll
            for (int i = 0; i < 4; ++i) {
                int row = mt * 16 + lgrp * 4 + i;
                int t = base + OFFSET + row; if (t >= NPIX) t -= NPIX;
                size_t idx = (size_t)t * 128 + coln;
                h[idx] = h[idx] + bb + c[i];
            }
        }
    }
}

// ---------------- MLP block: h += mlp2(gelu(mlp1(ln2(h))))
__global__ __launch_bounds__(256, 3) void k_mlp(
    float* __restrict__ h,
    const float* __restrict__ g, const float* __restrict__ be,
    const bf16* __restrict__ w1t, const float* __restrict__ b1,
    const bf16* __restrict__ w2t, const float* __restrict__ b2)
{
    __shared__ bf16 xn[8192];
    __shared__ bf16 uc[8192];
    __shared__ bf16 wb[8192];
    const int tid = threadIdx.x, base = blockIdx.x * 64;
    const int wid = tid >> 6, lane = tid & 63, lrow = lane & 15, lgrp = lane >> 4;

    {   // LayerNorm -> xn
        const int r = tid >> 2, c0 = (tid & 3) * 32;
        const float* hp = h + (size_t)(base + r) * 128 + c0;
        float v[32];
#pragma unroll
        for (int i = 0; i < 8; ++i) {
            float4 t4 = reinterpret_cast<const float4*>(hp)[i];
            v[4*i+0] = t4.x; v[4*i+1] = t4.y; v[4*i+2] = t4.z; v[4*i+3] = t4.w;
        }
        float s = 0.f;
#pragma unroll
        for (int i = 0; i < 32; ++i) s += v[i];
        s += __shfl_xor(s, 1, 64); s += __shfl_xor(s, 2, 64);
        float mu = s * (1.f / 128.f);
        float var = 0.f;
#pragma unroll
        for (int i = 0; i < 32; ++i) { float d = v[i] - mu; var += d * d; }
        var += __shfl_xor(var, 1, 64); var += __shfl_xor(var, 2, 64);
        float rstd = rsqrtf(var * (1.f / 128.f) + 1e-5f);
#pragma unroll
        for (int gph = 0; gph < 4; ++gph) {
            short8 w;
#pragma unroll
            for (int j = 0; j < 8; ++j) {
                int c = c0 + gph * 8 + j;
                w[j] = bfbits((v[gph * 8 + j] - mu) * rstd * g[c] + be[c]);
            }
            *reinterpret_cast<short8*>(&xn[r * 128 + swz(r, c0 + gph * 8)]) = w;
        }
    }
    lds_fence();

    short8 a1[4];
#pragma unroll
    for (int kk = 0; kk < 4; ++kk)
        a1[kk] = ldsA(xn, wid * 16 + lrow, kk * 32 + lgrp * 8);

    f32x4 acc2[8];
#pragma unroll
    for (int j = 0; j < 8; ++j) acc2[j] = (f32x4){0.f, 0.f, 0.f, 0.f};

    for (int kc = 0; kc < 4; ++kc) {
        // ---- mlp1: u-chunk cols [kc*128, +128), two 64-col halves
#pragma unroll
        for (int h1 = 0; h1 < 2; ++h1) {
            __syncthreads();
            stage_w(w1t + (size_t)(kc * 128 + h1 * 64) * 128, 128, wb, tid);
            __syncthreads();
#pragma unroll
            for (int nt = 0; nt < 4; ++nt) {
                f32x4 c = {0.f, 0.f, 0.f, 0.f};
#pragma unroll
                for (int kk = 0; kk < 4; ++kk) {
                    short8 bv = ldsA(wb, nt * 16 + lrow, kk * 32 + lgrp * 8);
                    c = __builtin_amdgcn_mfma_f32_16x16x32_bf16(a1[kk], bv, c, 0, 0, 0);
                }
                int ucol = h1 * 64 + nt * 16 + lrow;
                float bb = b1[kc * 128 + ucol];
#pragma unroll
                for (int i = 0; i < 4; ++i) {
                    int row = wid * 16 + lgrp * 4 + i;
                    uc[row * 128 + swz(row, ucol)] = __float2bfloat16(gelu_f(c[i] + bb));
                }
            }
        }
        lds_fence();
        short8 au[4];
#pragma unroll
        for (int kk = 0; kk < 4; ++kk)
            au[kk] = ldsA(uc, wid * 16 + lrow, kk * 32 + lgrp * 8);

        // ---- mlp2 partial: acc2 += u-chunk @ w2[:, kc-chunk]
#pragma unroll
        for (int h2 = 0; h2 < 2; ++h2) {
            __syncthreads();
            stage_w(w2t + (size_t)(h2 * 64) * 512 + kc * 128, 512, wb, tid);
            __syncthreads();
#pragma unroll
            for (int nt = 0; nt < 4; ++nt) {
#pragma unroll
                for (int kk = 0; kk < 4; ++kk) {
                    short8 bv = ldsA(wb, nt * 16 + lrow, kk * 32 + lgrp * 8);
                    acc2[h2 * 4 + nt] =
                        __builtin_amdgcn_mfma_f32_16x16x32_bf16(au[kk], bv, acc2[h2 * 4 + nt], 0, 0, 0);
                }
            }
        }
    }
#pragma unroll
    for (int j = 0; j < 8; ++j) {
        int col = (j >> 2) * 64 + (j & 3) * 16 + lrow;
        float bb = b2[col];
#pragma unroll
        for (int i = 0; i < 4; ++i) {
            size_t idx = (size_t)(base + wid * 16 + lgrp * 4 + i) * 128 + col;
            h[idx] = h[idx] + bb + acc2[j][i];
        }
    }
}

// ---------------- ff2: out = x + h @ w_ff2 + b
__global__ __launch_bounds__(256, 4) void k_ff2(
    const float* __restrict__ x, const float* __restrict__ hin,
    const bf16* __restrict__ wt, const float* __restrict__ b,
    float* __restrict__ out)
{
    __shared__ bf16 hsb[8192];
    __shared__ bf16 wb[8192];
    const int tid = threadIdx.x, base = blockIdx.x * 64;
    const int wid = tid >> 6, lane = tid & 63, lrow = lane & 15, lgrp = lane >> 4;

    {   // h -> hsb (bf16, swizzled): 4 thr/row, 4 groups of 8
        int row = tid >> 2, q = tid & 3;
#pragma unroll
        for (int s = 0; s < 4; ++s) {
            int g = q + s * 4;
            const float4* src = reinterpret_cast<const float4*>(hin + (size_t)(base + row) * 128 + g * 8);
            float4 v0 = src[0], v1 = src[1];
            short8 w;
            w[0] = bfbits(v0.x); w[1] = bfbits(v0.y); w[2] = bfbits(v0.z); w[3] = bfbits(v0.w);
            w[4] = bfbits(v1.x); w[5] = bfbits(v1.y); w[6] = bfbits(v1.z); w[7] = bfbits(v1.w);
            *reinterpret_cast<short8*>(&hsb[row * 128 + swz(row, g * 8)]) = w;
        }
    }
    stage_w(wt, 128, wb, tid);
    __syncthreads();

    short8 a[4];
#pragma unroll
    for (int kk = 0; kk < 4; ++kk)
        a[kk] = ldsA(hsb, wid * 16 + lrow, kk * 32 + lgrp * 8);
#pragma unroll
    for (int nt = 0; nt < 4; ++nt) {
        f32x4 c = {0.f, 0.f, 0.f, 0.f};
#pragma unroll
        for (int kk = 0; kk < 4; ++kk) {
            short8 bv = ldsA(wb, nt * 16 + lrow, kk * 32 + lgrp * 8);
            c = __builtin_amdgcn_mfma_f32_16x16x32_bf16(a[kk], bv, c, 0, 0, 0);
        }
        int col = nt * 16 + lrow;
        float bb = b[col];
#pragma unroll
        for (int i = 0; i < 4; ++i) {
            size_t gidx = (size_t)(base + wid * 16 + lgrp * 4 + i) * 64 + col;
            out[gidx] = x[gidx] + bb + c[i];
        }
    }
}

extern "C" void kernel_launch(void* const* d_in, const int* in_sizes, int n_in,
                              void* d_out, int out_size, void* d_ws, size_t ws_size,
                              hipStream_t stream) {
    (void)in_sizes; (void)n_in; (void)out_size; (void)ws_size;
    const float* x      = (const float*)d_in[0];
    const float* w_ff1  = (const float*)d_in[1];
    const float* b_ff1  = (const float*)d_in[2];
    const float* ln1_g  = (const float*)d_in[3];
    const float* ln1_b  = (const float*)d_in[4];
    const float* w_qkv  = (const float*)d_in[5];
    const float* b_qkv  = (const float*)d_in[6];
    const float* w_proj = (const float*)d_in[7];
    const float* b_proj = (const float*)d_in[8];
    const float* ln2_g  = (const float*)d_in[9];
    const float* ln2_b  = (const float*)d_in[10];
    const float* w_mlp1 = (const float*)d_in[11];
    const float* b_mlp1 = (const float*)d_in[12];
    const float* w_mlp2 = (const float*)d_in[13];
    const float* b_mlp2 = (const float*)d_in[14];
    const float* w_ff2  = (const float*)d_in[15];
    const float* b_ff2  = (const float*)d_in[16];
    float* out = (float*)d_out;

    float* h = (float*)d_ws;                                   // [NPIX,128] fp32
    bf16* wbf = (bf16*)((char*)d_ws + (size_t)NPIX * 128 * 4);
    bf16* ff1t  = wbf;            // [128][64]
    bf16* qkvt  = wbf + 8192;     // 2x[384][128]
    bf16* projt = wbf + 106496;   // 2x[128][128]
    bf16* mlp1t = wbf + 139264;   // 2x[512][128]
    bf16* mlp2t = wbf + 270336;   // 2x[128][512]
    bf16* ff2t  = wbf + 401408;   // [64][128]

    dim3 blk(256);
    k_convert<<<1600, blk, 0, stream>>>(w_ff1, w_qkv, w_proj, w_mlp1, w_mlp2, w_ff2, wbf);

    const int NB = NPIX / 64;  // 3072
    k_ff1<<<NB, blk, 0, stream>>>(x, ff1t, b_ff1, h);

    k_attn<0><<<NB, blk, 0, stream>>>(h, ln1_g, ln1_b, qkvt, b_qkv, projt, b_proj);
    k_mlp<<<NB, blk, 0, stream>>>(h, ln2_g, ln2_b, mlp1t, b_mlp1, mlp2t, b_mlp2);

    k_attn<8><<<NB, blk, 0, stream>>>(h, ln1_g + 128, ln1_b + 128,
                                      qkvt + 49152, b_qkv + 384,
                                      projt + 16384, b_proj + 128);
    k_mlp<<<NB, blk, 0, stream>>>(h, ln2_g + 128, ln2_b + 128,
                                  mlp1t + 65536, b_mlp1 + 512,
                                  mlp2t + 65536, b_mlp2 + 128);

    k_ff2<<<NB, blk, 0, stream>>>(x, h, ff2t, b_ff2, out);
}

// Round 4
// 516.634 us; speedup vs baseline: 7.9548x; 1.0352x over previous
//
#include <hip/hip_runtime.h>
#include <hip/hip_bf16.h>
#include <math.h>

#define NPIX 196608
#define SCALE_Q 0.17677669529663687f

typedef __attribute__((ext_vector_type(4))) float f32x4;
typedef __attribute__((ext_vector_type(8))) short short8;
typedef __attribute__((ext_vector_type(4))) short short4v;
typedef __hip_bfloat16 bf16;

typedef __attribute__((address_space(1))) const void* as1_void;
typedef __attribute__((address_space(3))) void* as3_void;

__device__ __forceinline__ float gelu_f(float x) {
    float yy = 1.5957691216057308f * (x + 0.044715f * x * x * x);
    float e = __expf(yy);
    return x - x * __builtin_amdgcn_rcpf(e + 1.0f);
}

__device__ __forceinline__ short bfbits(float f) {
    bf16 h = __float2bfloat16(f);
    return *reinterpret_cast<short*>(&h);
}

// swizzled fragment read from [rows][128] bf16 tile (XOR el bits 3-5 with row&7)
__device__ __forceinline__ short8 ldsA(const bf16* buf, int row, int el) {
    return *reinterpret_cast<const short8*>(buf + row * 128 + (el ^ ((row & 7) << 3)));
}
__device__ __forceinline__ short8 ldsA64(const bf16* buf, int row, int el) {
    return *reinterpret_cast<const short8*>(buf + row * 64 + (el ^ ((row & 7) << 3)));
}
__device__ __forceinline__ short8 gld8(const bf16* p) {
    return *reinterpret_cast<const short8*>(p);
}

// async global->LDS copy of BYTES (linear image; source pre-swizzled at convert)
template <int BYTES>
__device__ __forceinline__ void stage_gll(const bf16* img, bf16* lds, int tid) {
    const int wid = tid >> 6, lane = tid & 63;
    constexpr int NI = BYTES / 4096;      // 1KB per wave-instr, 4 waves
    const char* g = (const char*)img + lane * 16;
    char* l = (char*)lds;
#pragma unroll
    for (int i = 0; i < NI; ++i) {
        int off = (wid * NI + i) * 1024;
        __builtin_amdgcn_global_load_lds((as1_void)(g + off), (as3_void)(l + off),
                                         16, 0, 0);
    }
}

__device__ __forceinline__ void vmwait0() {
    asm volatile("s_waitcnt vmcnt(0)" ::: "memory");
}

// ---------------- weight convert to bf16 images --------------------------
__global__ __launch_bounds__(256) void k_convert(
    const float* __restrict__ wff1, const float* __restrict__ wqkv,
    const float* __restrict__ wproj, const float* __restrict__ wmlp1,
    const float* __restrict__ wmlp2, const float* __restrict__ wff2,
    bf16* __restrict__ dst)
{
    int gid = blockIdx.x * 256 + threadIdx.x;
    if (gid < 8192) {                       // ff1img [128 n][64 ki] swizzled
        int n = gid >> 6, ki = gid & 63, k = ki ^ ((n & 7) << 3);
        dst[gid] = __float2bfloat16(wff1[k * 128 + n]);
    } else if (gid < 106496) {              // qkvt linear [l][384 n][128 k]
        int r = gid - 8192; int l = r / 49152; r -= l * 49152;
        int n = r >> 7, k = r & 127;
        dst[gid] = __float2bfloat16(wqkv[l * 49152 + k * 384 + n]);
    } else if (gid < 139264) {              // projt linear [l][128 n][128 k]
        int r = gid - 106496; int l = r / 16384; r -= l * 16384;
        int n = r >> 7, k = r & 127;
        dst[gid] = __float2bfloat16(wproj[l * 16384 + k * 128 + n]);
    } else if (gid < 270336) {              // mlp1img [l][kc][128 n][128 ki] swz
        int r = gid - 139264; int l = r >> 16; r &= 65535;
        int kc = r >> 14; int rr = r & 16383;
        int n = rr >> 7, ki = rr & 127, k = ki ^ ((n & 7) << 3);
        dst[gid] = __float2bfloat16(wmlp1[l * 65536 + k * 512 + kc * 128 + n]);
    } else if (gid < 401408) {              // mlp2img [l][kc][128 n][128 ki] swz
        int r = gid - 270336; int l = r >> 16; r &= 65535;
        int kc = r >> 14; int rr = r & 16383;
        int n = rr >> 7, ki = rr & 127, k = ki ^ ((n & 7) << 3);
        dst[gid] = __float2bfloat16(wmlp2[l * 65536 + (kc * 128 + k) * 128 + n]);
    } else if (gid < 409600) {              // ff2img [64 n][128 ki] swz
        int r = gid - 401408;
        int n = r >> 7, ki = r & 127, k = ki ^ ((n & 7) << 3);
        dst[gid] = __float2bfloat16(wff2[k * 64 + n]);
    }
}

// ---------------- ff1: h = gelu(x @ w_ff1 + b), D[n][token] orientation ---
__global__ __launch_bounds__(256, 4) void k_ff1(
    const float* __restrict__ x, const bf16* __restrict__ wimg,
    const float* __restrict__ b, float* __restrict__ h)
{
    __shared__ __align__(16) bf16 xs[64 * 64];
    __shared__ __align__(16) bf16 wb[128 * 64];
    const int tid = threadIdx.x, base = blockIdx.x * 64;
    const int wid = tid >> 6, lrow = tid & 15, lgrp = (tid >> 4) & 3;

    stage_gll<16384>(wimg, wb, tid);
    {   // x -> xs (bf16, swizzled)
        int row = tid >> 2, q = tid & 3;
#pragma unroll
        for (int s = 0; s < 2; ++s) {
            int gg = q + s * 4;
            const float4* src = reinterpret_cast<const float4*>(x + (size_t)(base + row) * 64 + gg * 8);
            float4 v0 = src[0], v1 = src[1];
            short8 w;
            w[0] = bfbits(v0.x); w[1] = bfbits(v0.y); w[2] = bfbits(v0.z); w[3] = bfbits(v0.w);
            w[4] = bfbits(v1.x); w[5] = bfbits(v1.y); w[6] = bfbits(v1.z); w[7] = bfbits(v1.w);
            *reinterpret_cast<short8*>(&xs[row * 64 + ((gg * 8) ^ ((row & 7) << 3))]) = w;
        }
    }
    vmwait0();
    __syncthreads();

    short8 xb[4][2];
#pragma unroll
    for (int tt = 0; tt < 4; ++tt)
#pragma unroll
        for (int kk = 0; kk < 2; ++kk)
            xb[tt][kk] = ldsA64(xs, tt * 16 + lrow, kk * 32 + lgrp * 8);

#pragma unroll
    for (int nt = 0; nt < 2; ++nt) {
        const int cb = wid * 32 + nt * 16;
        float4 bv = *reinterpret_cast<const float4*>(b + cb + lgrp * 4);
        short8 wf[2];
#pragma unroll
        for (int kk = 0; kk < 2; ++kk)
            wf[kk] = ldsA64(wb, cb + lrow, kk * 32 + lgrp * 8);
#pragma unroll
        for (int tt = 0; tt < 4; ++tt) {
            f32x4 d = {0.f, 0.f, 0.f, 0.f};
#pragma unroll
            for (int kk = 0; kk < 2; ++kk)
                d = __builtin_amdgcn_mfma_f32_16x16x32_bf16(wf[kk], xb[tt][kk], d, 0, 0, 0);
            float4 ov;
            ov.x = gelu_f(d[0] + bv.x); ov.y = gelu_f(d[1] + bv.y);
            ov.z = gelu_f(d[2] + bv.z); ov.w = gelu_f(d[3] + bv.w);
            *reinterpret_cast<float4*>(h + (size_t)(base + tt * 16 + lrow) * 128 + cb + lgrp * 4) = ov;
        }
    }
}

// ---------------- attention block; OFFSET folds the cyclic shift ---------
template <int OFFSET>
__global__ __launch_bounds__(256, 3) void k_attn(
    float* __restrict__ h,
    const float* __restrict__ g, const float* __restrict__ be,
    const bf16* __restrict__ wqt, const float* __restrict__ bq,
    const bf16* __restrict__ wpt, const float* __restrict__ bp)
{
    __shared__ __align__(16) bf16 bufA[8192];   // xn -> q -> attn-out [tok][128]
    __shared__ __align__(16) bf16 bufB[8192];   // k [tok][128]; pl overlays own slice
    __shared__ __align__(16) bf16 vt[4][2048];  // [win][d 128][key 16]
    const int tid = threadIdx.x, base = blockIdx.x * 64;
    const int wid = tid >> 6, lrow = tid & 15, lgrp = (tid >> 4) & 3;

    {   // LayerNorm on shifted tokens -> bufA
        const int r = tid >> 2, c0 = (tid & 3) * 32;
        int t = base + OFFSET + r; if (t >= NPIX) t -= NPIX;
        const float* hp = h + (size_t)t * 128 + c0;
        float v[32];
#pragma unroll
        for (int i = 0; i < 8; ++i) {
            float4 t4 = reinterpret_cast<const float4*>(hp)[i];
            v[4*i+0] = t4.x; v[4*i+1] = t4.y; v[4*i+2] = t4.z; v[4*i+3] = t4.w;
        }
        float s = 0.f;
#pragma unroll
        for (int i = 0; i < 32; ++i) s += v[i];
        s += __shfl_xor(s, 1, 64); s += __shfl_xor(s, 2, 64);
        float mu = s * (1.f / 128.f);
        float var = 0.f;
#pragma unroll
        for (int i = 0; i < 32; ++i) { float d = v[i] - mu; var += d * d; }
        var += __shfl_xor(var, 1, 64); var += __shfl_xor(var, 2, 64);
        float rstd = rsqrtf(var * (1.f / 128.f) + 1e-5f);
#pragma unroll
        for (int gph = 0; gph < 4; ++gph) {
            short8 w;
#pragma unroll
            for (int j = 0; j < 8; ++j) {
                int c = c0 + gph * 8 + j;
                w[j] = bfbits((v[gph * 8 + j] - mu) * rstd * g[c] + be[c]);
            }
            *reinterpret_cast<short8*>(&bufA[r * 128 + ((c0 + gph * 8) ^ ((r & 7) << 3))]) = w;
        }
    }
    __syncthreads();

    short8 xb[4][4];
#pragma unroll
    for (int tt = 0; tt < 4; ++tt)
#pragma unroll
        for (int kk = 0; kk < 4; ++kk)
            xb[tt][kk] = ldsA(bufA, tt * 16 + lrow, kk * 32 + lgrp * 8);
    __syncthreads();   // all waves done reading xn before q overwrites bufA

    // ---- qkv: D[col][token]; wave owns 96 cols
    const int col0 = wid * 96;
#pragma unroll
    for (int nt = 0; nt < 6; ++nt) {
        const int cb = col0 + nt * 16;
        float4 bqv = *reinterpret_cast<const float4*>(bq + cb + lgrp * 4);
        short8 wf[4];
#pragma unroll
        for (int kk = 0; kk < 4; ++kk)
            wf[kk] = gld8(wqt + (size_t)(cb + lrow) * 128 + kk * 32 + lgrp * 8);
#pragma unroll
        for (int tt = 0; tt < 4; ++tt) {
            f32x4 d = {0.f, 0.f, 0.f, 0.f};
#pragma unroll
            for (int kk = 0; kk < 4; ++kk)
                d = __builtin_amdgcn_mfma_f32_16x16x32_bf16(wf[kk], xb[tt][kk], d, 0, 0, 0);
            int row = tt * 16 + lrow;
            if (cb < 128) {              // q (scaled)
                int c = cb + lgrp * 4;
                short4v pk;
                pk[0] = bfbits((d[0] + bqv.x) * SCALE_Q); pk[1] = bfbits((d[1] + bqv.y) * SCALE_Q);
                pk[2] = bfbits((d[2] + bqv.z) * SCALE_Q); pk[3] = bfbits((d[3] + bqv.w) * SCALE_Q);
                *reinterpret_cast<short4v*>(&bufA[row * 128 + (c ^ ((row & 7) << 3))]) = pk;
            } else if (cb < 256) {       // k
                int c = cb - 128 + lgrp * 4;
                short4v pk;
                pk[0] = bfbits(d[0] + bqv.x); pk[1] = bfbits(d[1] + bqv.y);
                pk[2] = bfbits(d[2] + bqv.z); pk[3] = bfbits(d[3] + bqv.w);
                *reinterpret_cast<short4v*>(&bufB[row * 128 + (c ^ ((row & 7) << 3))]) = pk;
            } else {                     // v -> vt[win][d][key]
                int db = cb - 256 + lgrp * 4;
                vt[tt][(db + 0) * 16 + lrow] = __float2bfloat16(d[0] + bqv.x);
                vt[tt][(db + 1) * 16 + lrow] = __float2bfloat16(d[1] + bqv.y);
                vt[tt][(db + 2) * 16 + lrow] = __float2bfloat16(d[2] + bqv.z);
                vt[tt][(db + 3) * 16 + lrow] = __float2bfloat16(d[3] + bqv.w);
            }
        }
    }
    __syncthreads();

    // ---- scores + softmax (own window per wave)
    float p[4][4];
#pragma unroll
    for (int hh = 0; hh < 4; ++hh) {
        short8 aq = ldsA(bufA, wid * 16 + lrow, hh * 32 + lgrp * 8);
        short8 bk = ldsA(bufB, wid * 16 + lrow, hh * 32 + lgrp * 8);
        f32x4 z = {0.f, 0.f, 0.f, 0.f};
        f32x4 s = __builtin_amdgcn_mfma_f32_16x16x32_bf16(aq, bk, z, 0, 0, 0);
#pragma unroll
        for (int i = 0; i < 4; ++i) {
            float m_ = s[i];
            m_ = fmaxf(m_, __shfl_xor(m_, 1, 64));
            m_ = fmaxf(m_, __shfl_xor(m_, 2, 64));
            m_ = fmaxf(m_, __shfl_xor(m_, 4, 64));
            m_ = fmaxf(m_, __shfl_xor(m_, 8, 64));
            float e = __expf(s[i] - m_);
            float sum = e;
            sum += __shfl_xor(sum, 1, 64);
            sum += __shfl_xor(sum, 2, 64);
            sum += __shfl_xor(sum, 4, 64);
            sum += __shfl_xor(sum, 8, 64);
            p[hh][i] = e * __builtin_amdgcn_rcpf(sum);
        }
    }
    // P -> own bufB slice: [hh][q-token 16][key 16]
    bf16* pl = bufB + wid * 2048;
#pragma unroll
    for (int hh = 0; hh < 4; ++hh)
#pragma unroll
        for (int i = 0; i < 4; ++i)
            pl[hh * 256 + (lgrp * 4 + i) * 16 + lrow] = __float2bfloat16(p[hh][i]);

    // ---- PV: D[d][token] via zero-padded K=32 (keys 16..31 = zero regs)
    short8 z8 = {0, 0, 0, 0, 0, 0, 0, 0};
#pragma unroll
    for (int dt = 0; dt < 8; ++dt) {
        int hh = dt >> 1;
        short8 av = z8, bv = z8;
        if (lgrp < 2) {
            av = *reinterpret_cast<const short8*>(&vt[wid][(dt * 16 + lrow) * 16 + lgrp * 8]);
            bv = *reinterpret_cast<const short8*>(&pl[hh * 256 + lrow * 16 + lgrp * 8]);
        }
        f32x4 z = {0.f, 0.f, 0.f, 0.f};
        f32x4 o = __builtin_amdgcn_mfma_f32_16x16x32_bf16(av, bv, z, 0, 0, 0);
        int row = wid * 16 + lrow;
        int c = dt * 16 + lgrp * 4;
        short4v pk;
        pk[0] = bfbits(o[0]); pk[1] = bfbits(o[1]); pk[2] = bfbits(o[2]); pk[3] = bfbits(o[3]);
        *reinterpret_cast<short4v*>(&bufA[row * 128 + (c ^ ((row & 7) << 3))]) = pk;
    }
    __syncthreads();

    // ---- proj: D[n][token] + residual (float4 RMW)
    short8 af[4][4];
#pragma unroll
    for (int tt = 0; tt < 4; ++tt)
#pragma unroll
        for (int kk = 0; kk < 4; ++kk)
            af[tt][kk] = ldsA(bufA, tt * 16 + lrow, kk * 32 + lgrp * 8);
    const int pc = wid * 32;
#pragma unroll
    for (int nt = 0; nt < 2; ++nt) {
        const int cb = pc + nt * 16;
        float4 bpv = *reinterpret_cast<const float4*>(bp + cb + lgrp * 4);
        short8 wf[4];
#pragma unroll
        for (int kk = 0; kk < 4; ++kk)
            wf[kk] = gld8(wpt + (size_t)(cb + lrow) * 128 + kk * 32 + lgrp * 8);
#pragma unroll
        for (int tt = 0; tt < 4; ++tt) {
            f32x4 d = {0.f, 0.f, 0.f, 0.f};
#pragma unroll
            for (int kk = 0; kk < 4; ++kk)
                d = __builtin_amdgcn_mfma_f32_16x16x32_bf16(wf[kk], af[tt][kk], d, 0, 0, 0);
            int tok = base + OFFSET + tt * 16 + lrow; if (tok >= NPIX) tok -= NPIX;
            float* hp = h + (size_t)tok * 128 + cb + lgrp * 4;
            float4 hv = *reinterpret_cast<float4*>(hp);
            hv.x += bpv.x + d[0]; hv.y += bpv.y + d[1];
            hv.z += bpv.z + d[2]; hv.w += bpv.w + d[3];
            *reinterpret_cast<float4*>(hp) = hv;
        }
    }
}

// ---------------- MLP block: h += mlp2(gelu(mlp1(ln2(h)))) ---------------
__global__ __launch_bounds__(256, 2) void k_mlp(
    float* __restrict__ h,
    const float* __restrict__ g, const float* __restrict__ be,
    const bf16* __restrict__ w1img, const float* __restrict__ b1,
    const bf16* __restrict__ w2img, const float* __restrict__ b2)
{
    __shared__ __align__(16) bf16 xn[64 * 128];
    __shared__ __align__(16) bf16 uc[64 * 128];
    __shared__ __align__(16) bf16 wb[128 * 128];
    const int tid = threadIdx.x, base = blockIdx.x * 64;
    const int wid = tid >> 6, lrow = tid & 15, lgrp = (tid >> 4) & 3;

    stage_gll<32768>(w1img, wb, tid);      // chunk 0 weights, overlapped with LN

    {   // LayerNorm -> xn
        const int r = tid >> 2, c0 = (tid & 3) * 32;
        const float* hp = h + (size_t)(base + r) * 128 + c0;
        float v[32];
#pragma unroll
        for (int i = 0; i < 8; ++i) {
            float4 t4 = reinterpret_cast<const float4*>(hp)[i];
            v[4*i+0] = t4.x; v[4*i+1] = t4.y; v[4*i+2] = t4.z; v[4*i+3] = t4.w;
        }
        float s = 0.f;
#pragma unroll
        for (int i = 0; i < 32; ++i) s += v[i];
        s += __shfl_xor(s, 1, 64); s += __shfl_xor(s, 2, 64);
        float mu = s * (1.f / 128.f);
        float var = 0.f;
#pragma unroll
        for (int i = 0; i < 32; ++i) { float d = v[i] - mu; var += d * d; }
        var += __shfl_xor(var, 1, 64); var += __shfl_xor(var, 2, 64);
        float rstd = rsqrtf(var * (1.f / 128.f) + 1e-5f);
#pragma unroll
        for (int gph = 0; gph < 4; ++gph) {
            short8 w;
#pragma unroll
            for (int j = 0; j < 8; ++j) {
                int c = c0 + gph * 8 + j;
                w[j] = bfbits((v[gph * 8 + j] - mu) * rstd * g[c] + be[c]);
            }
            *reinterpret_cast<short8*>(&xn[r * 128 + ((c0 + gph * 8) ^ ((r & 7) << 3))]) = w;
        }
    }
    vmwait0();
    __syncthreads();                       // xn ready + wb(chunk0) landed

    short8 xb[4][4];
#pragma unroll
    for (int tt = 0; tt < 4; ++tt)
#pragma unroll
        for (int kk = 0; kk < 4; ++kk)
            xb[tt][kk] = ldsA(xn, tt * 16 + lrow, kk * 32 + lgrp * 8);

    f32x4 acc[2][4];
#pragma unroll
    for (int a = 0; a < 2; ++a)
#pragma unroll
        for (int t = 0; t < 4; ++t) acc[a][t] = (f32x4){0.f, 0.f, 0.f, 0.f};

    for (int kc = 0; kc < 4; ++kc) {
        // hoist mlp1 weight frags, then free wb for the mlp2 stage
        short8 wf[2][4];
#pragma unroll
        for (int nt = 0; nt < 2; ++nt)
#pragma unroll
            for (int kk = 0; kk < 4; ++kk)
                wf[nt][kk] = ldsA(wb, wid * 32 + nt * 16 + lrow, kk * 32 + lgrp * 8);
        __syncthreads();                                   // wb reads done
        stage_gll<32768>(w2img + kc * 16384, wb, tid);     // mlp2 weights (async)

        // mlp1 compute: u-chunk D[n][token] -> uc (b64 writes)
#pragma unroll
        for (int nt = 0; nt < 2; ++nt) {
            const int cl = wid * 32 + nt * 16;             // chunk-local col
            float4 bv = *reinterpret_cast<const float4*>(b1 + kc * 128 + cl + lgrp * 4);
#pragma unroll
            for (int tt = 0; tt < 4; ++tt) {
                f32x4 d = {0.f, 0.f, 0.f, 0.f};
#pragma unroll
                for (int kk = 0; kk < 4; ++kk)
                    d = __builtin_amdgcn_mfma_f32_16x16x32_bf16(wf[nt][kk], xb[tt][kk], d, 0, 0, 0);
                short4v pk;
                pk[0] = bfbits(gelu_f(d[0] + bv.x)); pk[1] = bfbits(gelu_f(d[1] + bv.y));
                pk[2] = bfbits(gelu_f(d[2] + bv.z)); pk[3] = bfbits(gelu_f(d[3] + bv.w));
                int row = tt * 16 + lrow;
                int c = cl + lgrp * 4;
                *reinterpret_cast<short4v*>(&uc[row * 128 + (c ^ ((row & 7) << 3))]) = pk;
            }
        }
        vmwait0();
        __syncthreads();                                   // uc visible + mlp2 wb landed

        // hoist u frags + mlp2 weight frags
        short8 uf[4][4];
#pragma unroll
        for (int tt = 0; tt < 4; ++tt)
#pragma unroll
            for (int kk = 0; kk < 4; ++kk)
                uf[tt][kk] = ldsA(uc, tt * 16 + lrow, kk * 32 + lgrp * 8);
        short8 wf2[2][4];
#pragma unroll
        for (int nt = 0; nt < 2; ++nt)
#pragma unroll
            for (int kk = 0; kk < 4; ++kk)
                wf2[nt][kk] = ldsA(wb, wid * 32 + nt * 16 + lrow, kk * 32 + lgrp * 8);
        __syncthreads();                                   // uc & wb reads done
        if (kc < 3) stage_gll<32768>(w1img + (kc + 1) * 16384, wb, tid);

#pragma unroll
        for (int nt = 0; nt < 2; ++nt)
#pragma unroll
            for (int tt = 0; tt < 4; ++tt)
#pragma unroll
                for (int kk = 0; kk < 4; ++kk)
                    acc[nt][tt] = __builtin_amdgcn_mfma_f32_16x16x32_bf16(
                        wf2[nt][kk], uf[tt][kk], acc[nt][tt], 0, 0, 0);
        vmwait0();
        __syncthreads();                                   // next mlp1 wb landed
    }

    // epilogue: h += b2 + acc  (float4 RMW; D[n][token])
#pragma unroll
    for (int nt = 0; nt < 2; ++nt) {
        const int n0 = wid * 32 + nt * 16 + lgrp * 4;
        float4 b2v = *reinterpret_cast<const float4*>(b2 + n0);
#pragma unroll
        for (int tt = 0; tt < 4; ++tt) {
            int tok = base + tt * 16 + lrow;
            float* hp = h + (size_t)tok * 128 + n0;
            float4 hv = *reinterpret_cast<float4*>(hp);
            hv.x += b2v.x + acc[nt][tt][0]; hv.y += b2v.y + acc[nt][tt][1];
            hv.z += b2v.z + acc[nt][tt][2]; hv.w += b2v.w + acc[nt][tt][3];
            *reinterpret_cast<float4*>(hp) = hv;
        }
    }
}

// ---------------- ff2: out = x + h @ w_ff2 + b, D[n][token] --------------
__global__ __launch_bounds__(256, 4) void k_ff2(
    const float* __restrict__ x, const float* __restrict__ hin,
    const bf16* __restrict__ wimg, const float* __restrict__ b,
    float* __restrict__ out)
{
    __shared__ __align__(16) bf16 hsb[64 * 128];
    __shared__ __align__(16) bf16 wb[64 * 128];
    const int tid = threadIdx.x, base = blockIdx.x * 64;
    const int wid = tid >> 6, lrow = tid & 15, lgrp = (tid >> 4) & 3;

    stage_gll<16384>(wimg, wb, tid);
    {   // h -> hsb (bf16, swizzled)
        int row = tid >> 2, q = tid & 3;
#pragma unroll
        for (int s = 0; s < 4; ++s) {
            int gg = q + s * 4;
            const float4* src = reinterpret_cast<const float4*>(hin + (size_t)(base + row) * 128 + gg * 8);
            float4 v0 = src[0], v1 = src[1];
            short8 w;
            w[0] = bfbits(v0.x); w[1] = bfbits(v0.y); w[2] = bfbits(v0.z); w[3] = bfbits(v0.w);
            w[4] = bfbits(v1.x); w[5] = bfbits(v1.y); w[6] = bfbits(v1.z); w[7] = bfbits(v1.w);
            *reinterpret_cast<short8*>(&hsb[row * 128 + ((gg * 8) ^ ((row & 7) << 3))]) = w;
        }
    }
    vmwait0();
    __syncthreads();

    short8 xf[4][4];
#pragma unroll
    for (int tt = 0; tt < 4; ++tt)
#pragma unroll
        for (int kk = 0; kk < 4; ++kk)
            xf[tt][kk] = ldsA(hsb, tt * 16 + lrow, kk * 32 + lgrp * 8);

    const int cb = wid * 16;
    float4 bv = *reinterpret_cast<const float4*>(b + cb + lgrp * 4);
    short8 wf[4];
#pragma unroll
    for (int kk = 0; kk < 4; ++kk)
        wf[kk] = ldsA(wb, cb + lrow, kk * 32 + lgrp * 8);
#pragma unroll
    for (int tt = 0; tt < 4; ++tt) {
        f32x4 d = {0.f, 0.f, 0.f, 0.f};
#pragma unroll
        for (int kk = 0; kk < 4; ++kk)
            d = __builtin_amdgcn_mfma_f32_16x16x32_bf16(wf[kk], xf[tt][kk], d, 0, 0, 0);
        size_t gidx = (size_t)(base + tt * 16 + lrow) * 64 + cb + lgrp * 4;
        float4 xv = *reinterpret_cast<const float4*>(x + gidx);
        float4 ov;
        ov.x = xv.x + bv.x + d[0]; ov.y = xv.y + bv.y + d[1];
        ov.z = xv.z + bv.z + d[2]; ov.w = xv.w + bv.w + d[3];
        *reinterpret_cast<float4*>(out + gidx) = ov;
    }
}

extern "C" void kernel_launch(void* const* d_in, const int* in_sizes, int n_in,
                              void* d_out, int out_size, void* d_ws, size_t ws_size,
                              hipStream_t stream) {
    (void)in_sizes; (void)n_in; (void)out_size; (void)ws_size;
    const float* x      = (const float*)d_in[0];
    const float* w_ff1  = (const float*)d_in[1];
    const float* b_ff1  = (const float*)d_in[2];
    const float* ln1_g  = (const float*)d_in[3];
    const float* ln1_b  = (const float*)d_in[4];
    const float* w_qkv  = (const float*)d_in[5];
    const float* b_qkv  = (const float*)d_in[6];
    const float* w_proj = (const float*)d_in[7];
    const float* b_proj = (const float*)d_in[8];
    const float* ln2_g  = (const float*)d_in[9];
    const float* ln2_b  = (const float*)d_in[10];
    const float* w_mlp1 = (const float*)d_in[11];
    const float* b_mlp1 = (const float*)d_in[12];
    const float* w_mlp2 = (const float*)d_in[13];
    const float* b_mlp2 = (const float*)d_in[14];
    const float* w_ff2  = (const float*)d_in[15];
    const float* b_ff2  = (const float*)d_in[16];
    float* out = (float*)d_out;

    float* h = (float*)d_ws;                                   // [NPIX,128] fp32
    bf16* wbf = (bf16*)((char*)d_ws + (size_t)NPIX * 128 * 4);
    bf16* ff1img  = wbf;            // [128][64] swz
    bf16* qkvt    = wbf + 8192;     // 2x[384][128] linear
    bf16* projt   = wbf + 106496;   // 2x[128][128] linear
    bf16* mlp1img = wbf + 139264;   // 2x[4][128][128] swz
    bf16* mlp2img = wbf + 270336;   // 2x[4][128][128] swz
    bf16* ff2img  = wbf + 401408;   // [64][128] swz

    dim3 blk(256);
    k_convert<<<1600, blk, 0, stream>>>(w_ff1, w_qkv, w_proj, w_mlp1, w_mlp2, w_ff2, wbf);

    const int NB = NPIX / 64;  // 3072
    k_ff1<<<NB, blk, 0, stream>>>(x, ff1img, b_ff1, h);

    k_attn<0><<<NB, blk, 0, stream>>>(h, ln1_g, ln1_b, qkvt, b_qkv, projt, b_proj);
    k_mlp<<<NB, blk, 0, stream>>>(h, ln2_g, ln2_b, mlp1img, b_mlp1, mlp2img, b_mlp2);

    k_attn<8><<<NB, blk, 0, stream>>>(h, ln1_g + 128, ln1_b + 128,
                                      qkvt + 49152, b_qkv + 384,
                                      projt + 16384, b_proj + 128);
    k_mlp<<<NB, blk, 0, stream>>>(h, ln2_g + 128, ln2_b + 128,
                                  mlp1img + 65536, b_mlp1 + 512,
                                  mlp2img + 65536, b_mlp2 + 128);

    k_ff2<<<NB, blk, 0, stream>>>(x, h, ff2img, b_ff2, out);
}

// Round 5
// 513.230 us; speedup vs baseline: 8.0076x; 1.0066x over previous
//
#include <hip/hip_runtime.h>
#include <hip/hip_bf16.h>
#include <math.h>

#define NPIX 196608
#define SCALE_Q 0.17677669529663687f

typedef __attribute__((ext_vector_type(4))) float f32x4;
typedef __attribute__((ext_vector_type(8))) short short8;
typedef __attribute__((ext_vector_type(4))) short short4v;
typedef __hip_bfloat16 bf16;

typedef __attribute__((address_space(1))) const void* as1_void;
typedef __attribute__((address_space(3))) void* as3_void;

__device__ __forceinline__ float gelu_f(float x) {
    float yy = 1.5957691216057308f * (x + 0.044715f * x * x * x);
    float e = __expf(yy);
    return x - x * __builtin_amdgcn_rcpf(e + 1.0f);
}

__device__ __forceinline__ short bfbits(float f) {
    bf16 h = __float2bfloat16(f);
    return *reinterpret_cast<short*>(&h);
}

__device__ __forceinline__ short8 ldsA(const bf16* buf, int row, int el) {
    return *reinterpret_cast<const short8*>(buf + row * 128 + (el ^ ((row & 7) << 3)));
}
__device__ __forceinline__ short8 ldsA64(const bf16* buf, int row, int el) {
    return *reinterpret_cast<const short8*>(buf + row * 64 + (el ^ ((row & 7) << 3)));
}
__device__ __forceinline__ short8 gld8(const bf16* p) {
    return *reinterpret_cast<const short8*>(p);
}

template <int BYTES>
__device__ __forceinline__ void stage_gll(const bf16* img, bf16* lds, int tid) {
    const int wid = tid >> 6, lane = tid & 63;
    constexpr int NI = BYTES / 4096;
    const char* g = (const char*)img + lane * 16;
    char* l = (char*)lds;
#pragma unroll
    for (int i = 0; i < NI; ++i) {
        int off = (wid * NI + i) * 1024;
        __builtin_amdgcn_global_load_lds((as1_void)(g + off), (as3_void)(l + off),
                                         16, 0, 0);
    }
}

__device__ __forceinline__ void vmwait0() {
    asm volatile("s_waitcnt vmcnt(0)" ::: "memory");
}

// ---------------- weight convert to bf16 images --------------------------
__global__ __launch_bounds__(256) void k_convert(
    const float* __restrict__ wff1, const float* __restrict__ wqkv,
    const float* __restrict__ wproj, const float* __restrict__ wmlp1,
    const float* __restrict__ wmlp2, const float* __restrict__ wff2,
    bf16* __restrict__ dst)
{
    int gid = blockIdx.x * 256 + threadIdx.x;
    if (gid < 8192) {                       // ff1img [128 n][64 ki] swizzled
        int n = gid >> 6, ki = gid & 63, k = ki ^ ((n & 7) << 3);
        dst[gid] = __float2bfloat16(wff1[k * 128 + n]);
    } else if (gid < 106496) {              // qkvt linear [l][384 n][128 k]
        int r = gid - 8192; int l = r / 49152; r -= l * 49152;
        int n = r >> 7, k = r & 127;
        dst[gid] = __float2bfloat16(wqkv[l * 49152 + k * 384 + n]);
    } else if (gid < 139264) {              // projt linear [l][128 n][128 k]
        int r = gid - 106496; int l = r / 16384; r -= l * 16384;
        int n = r >> 7, k = r & 127;
        dst[gid] = __float2bfloat16(wproj[l * 16384 + k * 128 + n]);
    } else if (gid < 270336) {              // mlp1t linear [l][512 n][128 k]
        int r = gid - 139264; int l = r >> 16; r &= 65535;
        int n = r >> 7, k = r & 127;
        dst[gid] = __float2bfloat16(wmlp1[l * 65536 + k * 512 + n]);
    } else if (gid < 401408) {              // mlp2t linear [l][128 n][512 k]
        int r = gid - 270336; int l = r >> 16; r &= 65535;
        int n = r >> 9, k = r & 511;
        dst[gid] = __float2bfloat16(wmlp2[l * 65536 + k * 128 + n]);
    } else if (gid < 409600) {              // ff2img [64 n][128 ki] swz
        int r = gid - 401408;
        int n = r >> 7, ki = r & 127, k = ki ^ ((n & 7) << 3);
        dst[gid] = __float2bfloat16(wff2[k * 64 + n]);
    }
}

// ---------------- ff1: h = gelu(x @ w_ff1 + b), D[n][token] ---------------
__global__ __launch_bounds__(256, 4) void k_ff1(
    const float* __restrict__ x, const bf16* __restrict__ wimg,
    const float* __restrict__ b, float* __restrict__ h)
{
    __shared__ __align__(16) bf16 xs[64 * 64];
    __shared__ __align__(16) bf16 wb[128 * 64];
    const int tid = threadIdx.x, base = blockIdx.x * 64;
    const int wid = tid >> 6, lrow = tid & 15, lgrp = (tid >> 4) & 3;

    stage_gll<16384>(wimg, wb, tid);
    {
        int row = tid >> 2, q = tid & 3;
#pragma unroll
        for (int s = 0; s < 2; ++s) {
            int gg = q + s * 4;
            const float4* src = reinterpret_cast<const float4*>(x + (size_t)(base + row) * 64 + gg * 8);
            float4 v0 = src[0], v1 = src[1];
            short8 w;
            w[0] = bfbits(v0.x); w[1] = bfbits(v0.y); w[2] = bfbits(v0.z); w[3] = bfbits(v0.w);
            w[4] = bfbits(v1.x); w[5] = bfbits(v1.y); w[6] = bfbits(v1.z); w[7] = bfbits(v1.w);
            *reinterpret_cast<short8*>(&xs[row * 64 + ((gg * 8) ^ ((row & 7) << 3))]) = w;
        }
    }
    vmwait0();
    __syncthreads();

    short8 xb[4][2];
#pragma unroll
    for (int tt = 0; tt < 4; ++tt)
#pragma unroll
        for (int kk = 0; kk < 2; ++kk)
            xb[tt][kk] = ldsA64(xs, tt * 16 + lrow, kk * 32 + lgrp * 8);

#pragma unroll
    for (int nt = 0; nt < 2; ++nt) {
        const int cb = wid * 32 + nt * 16;
        float4 bv = *reinterpret_cast<const float4*>(b + cb + lgrp * 4);
        short8 wf[2];
#pragma unroll
        for (int kk = 0; kk < 2; ++kk)
            wf[kk] = ldsA64(wb, cb + lrow, kk * 32 + lgrp * 8);
#pragma unroll
        for (int tt = 0; tt < 4; ++tt) {
            f32x4 d = {0.f, 0.f, 0.f, 0.f};
#pragma unroll
            for (int kk = 0; kk < 2; ++kk)
                d = __builtin_amdgcn_mfma_f32_16x16x32_bf16(wf[kk], xb[tt][kk], d, 0, 0, 0);
            float4 ov;
            ov.x = gelu_f(d[0] + bv.x); ov.y = gelu_f(d[1] + bv.y);
            ov.z = gelu_f(d[2] + bv.z); ov.w = gelu_f(d[3] + bv.w);
            *reinterpret_cast<float4*>(h + (size_t)(base + tt * 16 + lrow) * 128 + cb + lgrp * 4) = ov;
        }
    }
}

// ---------------- fused transformer block (attn + MLP) -------------------
template <int OFFSET>
__global__ __launch_bounds__(256, 3) void k_tblock(
    float* __restrict__ h,
    const float* __restrict__ g1, const float* __restrict__ be1,
    const bf16* __restrict__ wqt, const float* __restrict__ bq,
    const bf16* __restrict__ wpt, const float* __restrict__ bp,
    const float* __restrict__ g2, const float* __restrict__ be2,
    const bf16* __restrict__ w1t, const float* __restrict__ b1,
    const bf16* __restrict__ w2t, const float* __restrict__ b2)
{
    __shared__ __align__(16) bf16 bufA[8192];  // xn1 -> q -> attn-out -> u-chunk
    __shared__ __align__(16) bf16 bufB[8192];  // k -> P slices -> xn2
    __shared__ __align__(16) bf16 bufC[8192];  // vt -> LN2 partials
    const int tid = threadIdx.x, base = blockIdx.x * 64;
    const int wid = tid >> 6, lrow = tid & 15, lgrp = (tid >> 4) & 3;

    {   // ---- LN1 on shifted tokens -> bufA
        const int r = tid >> 2, c0 = (tid & 3) * 32;
        int t = base + OFFSET + r; if (t >= NPIX) t -= NPIX;
        const float* hp = h + (size_t)t * 128 + c0;
        float v[32];
#pragma unroll
        for (int i = 0; i < 8; ++i) {
            float4 t4 = reinterpret_cast<const float4*>(hp)[i];
            v[4*i+0] = t4.x; v[4*i+1] = t4.y; v[4*i+2] = t4.z; v[4*i+3] = t4.w;
        }
        float s = 0.f;
#pragma unroll
        for (int i = 0; i < 32; ++i) s += v[i];
        s += __shfl_xor(s, 1, 64); s += __shfl_xor(s, 2, 64);
        float mu = s * (1.f / 128.f);
        float var = 0.f;
#pragma unroll
        for (int i = 0; i < 32; ++i) { float d = v[i] - mu; var += d * d; }
        var += __shfl_xor(var, 1, 64); var += __shfl_xor(var, 2, 64);
        float rstd = rsqrtf(var * (1.f / 128.f) + 1e-5f);
#pragma unroll
        for (int gph = 0; gph < 4; ++gph) {
            short8 w;
#pragma unroll
            for (int j = 0; j < 8; ++j) {
                int c = c0 + gph * 8 + j;
                w[j] = bfbits((v[gph * 8 + j] - mu) * rstd * g1[c] + be1[c]);
            }
            *reinterpret_cast<short8*>(&bufA[r * 128 + ((c0 + gph * 8) ^ ((r & 7) << 3))]) = w;
        }
    }
    __syncthreads();

    short8 xb[4][4];
#pragma unroll
    for (int tt = 0; tt < 4; ++tt)
#pragma unroll
        for (int kk = 0; kk < 4; ++kk)
            xb[tt][kk] = ldsA(bufA, tt * 16 + lrow, kk * 32 + lgrp * 8);
    __syncthreads();   // xn1 reads done before q overwrites bufA

    // ---- qkv: D[col][token]; wave owns 96 cols; weights direct from L2
    const int col0 = wid * 96;
#pragma unroll
    for (int nt = 0; nt < 6; ++nt) {
        const int cb = col0 + nt * 16;
        float4 bqv = *reinterpret_cast<const float4*>(bq + cb + lgrp * 4);
        short8 wf[4];
#pragma unroll
        for (int kk = 0; kk < 4; ++kk)
            wf[kk] = gld8(wqt + (size_t)(cb + lrow) * 128 + kk * 32 + lgrp * 8);
        __builtin_amdgcn_s_setprio(1);
#pragma unroll
        for (int tt = 0; tt < 4; ++tt) {
            f32x4 d = {0.f, 0.f, 0.f, 0.f};
#pragma unroll
            for (int kk = 0; kk < 4; ++kk)
                d = __builtin_amdgcn_mfma_f32_16x16x32_bf16(wf[kk], xb[tt][kk], d, 0, 0, 0);
            int row = tt * 16 + lrow;
            if (cb < 128) {
                int c = cb + lgrp * 4;
                short4v pk;
                pk[0] = bfbits((d[0] + bqv.x) * SCALE_Q); pk[1] = bfbits((d[1] + bqv.y) * SCALE_Q);
                pk[2] = bfbits((d[2] + bqv.z) * SCALE_Q); pk[3] = bfbits((d[3] + bqv.w) * SCALE_Q);
                *reinterpret_cast<short4v*>(&bufA[row * 128 + (c ^ ((row & 7) << 3))]) = pk;
            } else if (cb < 256) {
                int c = cb - 128 + lgrp * 4;
                short4v pk;
                pk[0] = bfbits(d[0] + bqv.x); pk[1] = bfbits(d[1] + bqv.y);
                pk[2] = bfbits(d[2] + bqv.z); pk[3] = bfbits(d[3] + bqv.w);
                *reinterpret_cast<short4v*>(&bufB[row * 128 + (c ^ ((row & 7) << 3))]) = pk;
            } else {
                int db = cb - 256 + lgrp * 4;
                bufC[tt * 2048 + (db + 0) * 16 + lrow] = __float2bfloat16(d[0] + bqv.x);
                bufC[tt * 2048 + (db + 1) * 16 + lrow] = __float2bfloat16(d[1] + bqv.y);
                bufC[tt * 2048 + (db + 2) * 16 + lrow] = __float2bfloat16(d[2] + bqv.z);
                bufC[tt * 2048 + (db + 3) * 16 + lrow] = __float2bfloat16(d[3] + bqv.w);
            }
        }
        __builtin_amdgcn_s_setprio(0);
    }
    __syncthreads();

    // ---- scores + softmax (own window per wave)
    float p[4][4];
#pragma unroll
    for (int hh = 0; hh < 4; ++hh) {
        short8 aq = ldsA(bufA, wid * 16 + lrow, hh * 32 + lgrp * 8);
        short8 bk = ldsA(bufB, wid * 16 + lrow, hh * 32 + lgrp * 8);
        f32x4 z = {0.f, 0.f, 0.f, 0.f};
        f32x4 s = __builtin_amdgcn_mfma_f32_16x16x32_bf16(aq, bk, z, 0, 0, 0);
#pragma unroll
        for (int i = 0; i < 4; ++i) {
            float m_ = s[i];
            m_ = fmaxf(m_, __shfl_xor(m_, 1, 64));
            m_ = fmaxf(m_, __shfl_xor(m_, 2, 64));
            m_ = fmaxf(m_, __shfl_xor(m_, 4, 64));
            m_ = fmaxf(m_, __shfl_xor(m_, 8, 64));
            float e = __expf(s[i] - m_);
            float sum = e;
            sum += __shfl_xor(sum, 1, 64);
            sum += __shfl_xor(sum, 2, 64);
            sum += __shfl_xor(sum, 4, 64);
            sum += __shfl_xor(sum, 8, 64);
            p[hh][i] = e * __builtin_amdgcn_rcpf(sum);
        }
    }
    bf16* pl = bufB + wid * 2048;
#pragma unroll
    for (int hh = 0; hh < 4; ++hh)
#pragma unroll
        for (int i = 0; i < 4; ++i)
            pl[hh * 256 + (lgrp * 4 + i) * 16 + lrow] = __float2bfloat16(p[hh][i]);

    // ---- PV: D[d][token], keys 16..31 zero-padded via zero regs
    short8 z8 = {0, 0, 0, 0, 0, 0, 0, 0};
#pragma unroll
    for (int dt = 0; dt < 8; ++dt) {
        int hh = dt >> 1;
        short8 av = z8, bv = z8;
        if (lgrp < 2) {
            av = *reinterpret_cast<const short8*>(&bufC[wid * 2048 + (dt * 16 + lrow) * 16 + lgrp * 8]);
            bv = *reinterpret_cast<const short8*>(&pl[hh * 256 + lrow * 16 + lgrp * 8]);
        }
        f32x4 z = {0.f, 0.f, 0.f, 0.f};
        f32x4 o = __builtin_amdgcn_mfma_f32_16x16x32_bf16(av, bv, z, 0, 0, 0);
        int row = wid * 16 + lrow;
        int c = dt * 16 + lgrp * 4;
        short4v pk;
        pk[0] = bfbits(o[0]); pk[1] = bfbits(o[1]); pk[2] = bfbits(o[2]); pk[3] = bfbits(o[3]);
        *reinterpret_cast<short4v*>(&bufA[row * 128 + (c ^ ((row & 7) << 3))]) = pk;
    }
    __syncthreads();   // attn-out complete; vt/P reads done

    // ---- proj + h_old -> hres (registers); wave owns 32 out-cols
    short8 af[4][4];
#pragma unroll
    for (int tt = 0; tt < 4; ++tt)
#pragma unroll
        for (int kk = 0; kk < 4; ++kk)
            af[tt][kk] = ldsA(bufA, tt * 16 + lrow, kk * 32 + lgrp * 8);
    f32x4 hres[2][4];
#pragma unroll
    for (int nt = 0; nt < 2; ++nt) {
        const int cb = wid * 32 + nt * 16;
        float4 bpv = *reinterpret_cast<const float4*>(bp + cb + lgrp * 4);
        short8 wf[4];
#pragma unroll
        for (int kk = 0; kk < 4; ++kk)
            wf[kk] = gld8(wpt + (size_t)(cb + lrow) * 128 + kk * 32 + lgrp * 8);
#pragma unroll
        for (int tt = 0; tt < 4; ++tt) {
            f32x4 d = {0.f, 0.f, 0.f, 0.f};
#pragma unroll
            for (int kk = 0; kk < 4; ++kk)
                d = __builtin_amdgcn_mfma_f32_16x16x32_bf16(wf[kk], af[tt][kk], d, 0, 0, 0);
            int tok = base + OFFSET + tt * 16 + lrow; if (tok >= NPIX) tok -= NPIX;
            float4 hv = *reinterpret_cast<const float4*>(h + (size_t)tok * 128 + cb + lgrp * 4);
            f32x4 r;
            r[0] = hv.x + bpv.x + d[0]; r[1] = hv.y + bpv.y + d[1];
            r[2] = hv.z + bpv.z + d[2]; r[3] = hv.w + bpv.w + d[3];
            hres[nt][tt] = r;
        }
    }

    // ---- LN2: cross-wave reduction via bufC (vt dead)
    float2* ws = reinterpret_cast<float2*>(bufC);
#pragma unroll
    for (int tt = 0; tt < 4; ++tt) {
        float s = 0.f, q = 0.f;
#pragma unroll
        for (int nt = 0; nt < 2; ++nt)
#pragma unroll
            for (int i = 0; i < 4; ++i) { float v = hres[nt][tt][i]; s += v; q += v * v; }
        s += __shfl_xor(s, 16, 64); s += __shfl_xor(s, 32, 64);
        q += __shfl_xor(q, 16, 64); q += __shfl_xor(q, 32, 64);
        if (lgrp == 0) { float2 t2; t2.x = s; t2.y = q; ws[wid * 64 + tt * 16 + lrow] = t2; }
    }
    __syncthreads();
    float mu[4], rstd[4];
#pragma unroll
    for (int tt = 0; tt < 4; ++tt) {
        float s = 0.f, q = 0.f;
#pragma unroll
        for (int w = 0; w < 4; ++w) {
            float2 t2 = ws[w * 64 + tt * 16 + lrow];
            s += t2.x; q += t2.y;
        }
        float m = s * (1.f / 128.f);
        mu[tt] = m;
        rstd[tt] = rsqrtf(q * (1.f / 128.f) - m * m + 1e-5f);
    }
    float4 g2v[2], be2v[2];
#pragma unroll
    for (int nt = 0; nt < 2; ++nt) {
        g2v[nt]  = *reinterpret_cast<const float4*>(g2 + wid * 32 + nt * 16 + lgrp * 4);
        be2v[nt] = *reinterpret_cast<const float4*>(be2 + wid * 32 + nt * 16 + lgrp * 4);
    }
#pragma unroll
    for (int nt = 0; nt < 2; ++nt)
#pragma unroll
        for (int tt = 0; tt < 4; ++tt) {
            short4v pk;
            pk[0] = bfbits((hres[nt][tt][0] - mu[tt]) * rstd[tt] * g2v[nt].x + be2v[nt].x);
            pk[1] = bfbits((hres[nt][tt][1] - mu[tt]) * rstd[tt] * g2v[nt].y + be2v[nt].y);
            pk[2] = bfbits((hres[nt][tt][2] - mu[tt]) * rstd[tt] * g2v[nt].z + be2v[nt].z);
            pk[3] = bfbits((hres[nt][tt][3] - mu[tt]) * rstd[tt] * g2v[nt].w + be2v[nt].w);
            int row = tt * 16 + lrow;
            int c = wid * 32 + nt * 16 + lgrp * 4;
            *reinterpret_cast<short4v*>(&bufB[row * 128 + (c ^ ((row & 7) << 3))]) = pk;
        }
    __syncthreads();

    short8 xb2[4][4];
#pragma unroll
    for (int tt = 0; tt < 4; ++tt)
#pragma unroll
        for (int kk = 0; kk < 4; ++kk)
            xb2[tt][kk] = ldsA(bufB, tt * 16 + lrow, kk * 32 + lgrp * 8);

    f32x4 acc2[2][4];
#pragma unroll
    for (int nt = 0; nt < 2; ++nt)
#pragma unroll
        for (int tt = 0; tt < 4; ++tt) acc2[nt][tt] = (f32x4){0.f, 0.f, 0.f, 0.f};

    // ---- MLP over 4 u-chunks of 128; u through bufA; weights direct from L2
    for (int ch = 0; ch < 4; ++ch) {
#pragma unroll
        for (int nt = 0; nt < 2; ++nt) {
            const int r0 = ch * 128 + wid * 32 + nt * 16;
            float4 bv = *reinterpret_cast<const float4*>(b1 + r0 + lgrp * 4);
            short8 wf[4];
#pragma unroll
            for (int kk = 0; kk < 4; ++kk)
                wf[kk] = gld8(w1t + (size_t)(r0 + lrow) * 128 + kk * 32 + lgrp * 8);
            __builtin_amdgcn_s_setprio(1);
#pragma unroll
            for (int tt = 0; tt < 4; ++tt) {
                f32x4 d = {0.f, 0.f, 0.f, 0.f};
#pragma unroll
                for (int kk = 0; kk < 4; ++kk)
                    d = __builtin_amdgcn_mfma_f32_16x16x32_bf16(wf[kk], xb2[tt][kk], d, 0, 0, 0);
                short4v pk;
                pk[0] = bfbits(gelu_f(d[0] + bv.x)); pk[1] = bfbits(gelu_f(d[1] + bv.y));
                pk[2] = bfbits(gelu_f(d[2] + bv.z)); pk[3] = bfbits(gelu_f(d[3] + bv.w));
                int row = tt * 16 + lrow;
                int c = wid * 32 + nt * 16 + lgrp * 4;
                *reinterpret_cast<short4v*>(&bufA[row * 128 + (c ^ ((row & 7) << 3))]) = pk;
            }
            __builtin_amdgcn_s_setprio(0);
        }
        __syncthreads();     // u-chunk complete

        short8 wf2[2][4];
#pragma unroll
        for (int nt = 0; nt < 2; ++nt)
#pragma unroll
            for (int kk = 0; kk < 4; ++kk)
                wf2[nt][kk] = gld8(w2t + (size_t)(wid * 32 + nt * 16 + lrow) * 512 +
                                   ch * 128 + kk * 32 + lgrp * 8);
        __builtin_amdgcn_s_setprio(1);
#pragma unroll
        for (int tt = 0; tt < 4; ++tt) {
            short8 uf[4];
#pragma unroll
            for (int kk = 0; kk < 4; ++kk)
                uf[kk] = ldsA(bufA, tt * 16 + lrow, kk * 32 + lgrp * 8);
#pragma unroll
            for (int nt = 0; nt < 2; ++nt)
#pragma unroll
                for (int kk = 0; kk < 4; ++kk)
                    acc2[nt][tt] = __builtin_amdgcn_mfma_f32_16x16x32_bf16(
                        wf2[nt][kk], uf[kk], acc2[nt][tt], 0, 0, 0);
        }
        __builtin_amdgcn_s_setprio(0);
        __syncthreads();     // u-chunk reads done before next overwrite
    }

    // ---- epilogue: h = hres + b2 + mlp2   (single global write)
#pragma unroll
    for (int nt = 0; nt < 2; ++nt) {
        const int n0 = wid * 32 + nt * 16 + lgrp * 4;
        float4 b2v = *reinterpret_cast<const float4*>(b2 + n0);
#pragma unroll
        for (int tt = 0; tt < 4; ++tt) {
            int tok = base + OFFSET + tt * 16 + lrow; if (tok >= NPIX) tok -= NPIX;
            float4 ov;
            ov.x = hres[nt][tt][0] + b2v.x + acc2[nt][tt][0];
            ov.y = hres[nt][tt][1] + b2v.y + acc2[nt][tt][1];
            ov.z = hres[nt][tt][2] + b2v.z + acc2[nt][tt][2];
            ov.w = hres[nt][tt][3] + b2v.w + acc2[nt][tt][3];
            *reinterpret_cast<float4*>(h + (size_t)tok * 128 + n0) = ov;
        }
    }
}

// ---------------- ff2: out = x + h @ w_ff2 + b, D[n][token] --------------
__global__ __launch_bounds__(256, 4) void k_ff2(
    const float* __restrict__ x, const float* __restrict__ hin,
    const bf16* __restrict__ wimg, const float* __restrict__ b,
    float* __restrict__ out)
{
    __shared__ __align__(16) bf16 hsb[64 * 128];
    __shared__ __align__(16) bf16 wb[64 * 128];
    const int tid = threadIdx.x, base = blockIdx.x * 64;
    const int wid = tid >> 6, lrow = tid & 15, lgrp = (tid >> 4) & 3;

    stage_gll<16384>(wimg, wb, tid);
    {
        int row = tid >> 2, q = tid & 3;
#pragma unroll
        for (int s = 0; s < 4; ++s) {
            int gg = q + s * 4;
            const float4* src = reinterpret_cast<const float4*>(hin + (size_t)(base + row) * 128 + gg * 8);
            float4 v0 = src[0], v1 = src[1];
            short8 w;
            w[0] = bfbits(v0.x); w[1] = bfbits(v0.y); w[2] = bfbits(v0.z); w[3] = bfbits(v0.w);
            w[4] = bfbits(v1.x); w[5] = bfbits(v1.y); w[6] = bfbits(v1.z); w[7] = bfbits(v1.w);
            *reinterpret_cast<short8*>(&hsb[row * 128 + ((gg * 8) ^ ((row & 7) << 3))]) = w;
        }
    }
    vmwait0();
    __syncthreads();

    short8 xf[4][4];
#pragma unroll
    for (int tt = 0; tt < 4; ++tt)
#pragma unroll
        for (int kk = 0; kk < 4; ++kk)
            xf[tt][kk] = ldsA(hsb, tt * 16 + lrow, kk * 32 + lgrp * 8);

    const int cb = wid * 16;
    float4 bv = *reinterpret_cast<const float4*>(b + cb + lgrp * 4);
    short8 wf[4];
#pragma unroll
    for (int kk = 0; kk < 4; ++kk)
        wf[kk] = ldsA(wb, cb + lrow, kk * 32 + lgrp * 8);
#pragma unroll
    for (int tt = 0; tt < 4; ++tt) {
        f32x4 d = {0.f, 0.f, 0.f, 0.f};
#pragma unroll
        for (int kk = 0; kk < 4; ++kk)
            d = __builtin_amdgcn_mfma_f32_16x16x32_bf16(wf[kk], xf[tt][kk], d, 0, 0, 0);
        size_t gidx = (size_t)(base + tt * 16 + lrow) * 64 + cb + lgrp * 4;
        float4 xv = *reinterpret_cast<const float4*>(x + gidx);
        float4 ov;
        ov.x = xv.x + bv.x + d[0]; ov.y = xv.y + bv.y + d[1];
        ov.z = xv.z + bv.z + d[2]; ov.w = xv.w + bv.w + d[3];
        *reinterpret_cast<float4*>(out + gidx) = ov;
    }
}

extern "C" void kernel_launch(void* const* d_in, const int* in_sizes, int n_in,
                              void* d_out, int out_size, void* d_ws, size_t ws_size,
                              hipStream_t stream) {
    (void)in_sizes; (void)n_in; (void)out_size; (void)ws_size;
    const float* x      = (const float*)d_in[0];
    const float* w_ff1  = (const float*)d_in[1];
    const float* b_ff1  = (const float*)d_in[2];
    const float* ln1_g  = (const float*)d_in[3];
    const float* ln1_b  = (const float*)d_in[4];
    const float* w_qkv  = (const float*)d_in[5];
    const float* b_qkv  = (const float*)d_in[6];
    const float* w_proj = (const float*)d_in[7];
    const float* b_proj = (const float*)d_in[8];
    const float* ln2_g  = (const float*)d_in[9];
    const float* ln2_b  = (const float*)d_in[10];
    const float* w_mlp1 = (const float*)d_in[11];
    const float* b_mlp1 = (const float*)d_in[12];
    const float* w_mlp2 = (const float*)d_in[13];
    const float* b_mlp2 = (const float*)d_in[14];
    const float* w_ff2  = (const float*)d_in[15];
    const float* b_ff2  = (const float*)d_in[16];
    float* out = (float*)d_out;

    float* h = (float*)d_ws;                                   // [NPIX,128] fp32
    bf16* wbf = (bf16*)((char*)d_ws + (size_t)NPIX * 128 * 4);
    bf16* ff1img = wbf;            // [128][64] swz
    bf16* qkvt   = wbf + 8192;     // 2x[384][128] linear
    bf16* projt  = wbf + 106496;   // 2x[128][128] linear
    bf16* mlp1t  = wbf + 139264;   // 2x[512][128] linear
    bf16* mlp2t  = wbf + 270336;   // 2x[128][512] linear
    bf16* ff2img = wbf + 401408;   // [64][128] swz

    dim3 blk(256);
    k_convert<<<1600, blk, 0, stream>>>(w_ff1, w_qkv, w_proj, w_mlp1, w_mlp2, w_ff2, wbf);

    const int NB = NPIX / 64;  // 3072
    k_ff1<<<NB, blk, 0, stream>>>(x, ff1img, b_ff1, h);

    k_tblock<0><<<NB, blk, 0, stream>>>(h,
        ln1_g, ln1_b, qkvt, b_qkv, projt, b_proj,
        ln2_g, ln2_b, mlp1t, b_mlp1, mlp2t, b_mlp2);

    k_tblock<8><<<NB, blk, 0, stream>>>(h,
        ln1_g + 128, ln1_b + 128, qkvt + 49152, b_qkv + 384, projt + 16384, b_proj + 128,
        ln2_g + 128, ln2_b + 128, mlp1t + 65536, b_mlp1 + 512, mlp2t + 65536, b_mlp2 + 128);

    k_ff2<<<NB, blk, 0, stream>>>(x, h, ff2img, b_ff2, out);
}

// Round 6
// 487.967 us; speedup vs baseline: 8.4222x; 1.0518x over previous
//
#include <hip/hip_runtime.h>
#include <hip/hip_bf16.h>
#include <math.h>

#define NPIX 196608
#define SCALE_Q 0.17677669529663687f

typedef __attribute__((ext_vector_type(4))) float f32x4;
typedef __attribute__((ext_vector_type(8))) short short8;
typedef __attribute__((ext_vector_type(4))) short short4v;
typedef __hip_bfloat16 bf16;

__device__ __forceinline__ float gelu_f(float x) {
    float yy = 1.5957691216057308f * (x + 0.044715f * x * x * x);
    float e = __expf(yy);
    return x - x * __builtin_amdgcn_rcpf(e + 1.0f);
}

__device__ __forceinline__ short bfbits(float f) {
    bf16 h = __float2bfloat16(f);
    return *reinterpret_cast<short*>(&h);
}

__device__ __forceinline__ short8 ldsA(const bf16* buf, int row, int el) {
    return *reinterpret_cast<const short8*>(buf + row * 128 + (el ^ ((row & 7) << 3)));
}
__device__ __forceinline__ short8 ldsA64(const bf16* buf, int row, int el) {
    return *reinterpret_cast<const short8*>(buf + row * 64 + (el ^ ((row & 7) << 3)));
}
__device__ __forceinline__ short8 gld8(const bf16* p) {
    return *reinterpret_cast<const short8*>(p);
}

// ---------------- weight convert to bf16 transposed images (all linear) ---
__global__ __launch_bounds__(256) void k_convert(
    const float* __restrict__ wff1, const float* __restrict__ wqkv,
    const float* __restrict__ wproj, const float* __restrict__ wmlp1,
    const float* __restrict__ wmlp2, const float* __restrict__ wff2,
    bf16* __restrict__ dst)
{
    int gid = blockIdx.x * 256 + threadIdx.x;
    if (gid < 8192) {                       // ff1t [128 n][64 k]
        int n = gid >> 6, k = gid & 63;
        dst[gid] = __float2bfloat16(wff1[k * 128 + n]);
    } else if (gid < 106496) {              // qkvt [l][384 n][128 k]
        int r = gid - 8192; int l = r / 49152; r -= l * 49152;
        int n = r >> 7, k = r & 127;
        dst[gid] = __float2bfloat16(wqkv[l * 49152 + k * 384 + n]);
    } else if (gid < 139264) {              // projt [l][128 n][128 k]
        int r = gid - 106496; int l = r / 16384; r -= l * 16384;
        int n = r >> 7, k = r & 127;
        dst[gid] = __float2bfloat16(wproj[l * 16384 + k * 128 + n]);
    } else if (gid < 270336) {              // mlp1t [l][512 n][128 k]
        int r = gid - 139264; int l = r >> 16; r &= 65535;
        int n = r >> 7, k = r & 127;
        dst[gid] = __float2bfloat16(wmlp1[l * 65536 + k * 512 + n]);
    } else if (gid < 401408) {              // mlp2t [l][128 n][512 k]
        int r = gid - 270336; int l = r >> 16; r &= 65535;
        int n = r >> 9, k = r & 511;
        dst[gid] = __float2bfloat16(wmlp2[l * 65536 + k * 128 + n]);
    } else if (gid < 409600) {              // ff2t [64 n][128 k]
        int r = gid - 401408;
        int n = r >> 7, k = r & 127;
        dst[gid] = __float2bfloat16(wff2[k * 64 + n]);
    }
}

// ---------------- fused block kernel ------------------------------------
// MODE 0: ff1 fused at head (reads x), writes h at tail.
// MODE 1: reads h at head, ff2 fused at tail (writes out).
template <int OFFSET, int MODE>
__global__ __launch_bounds__(256, 3) void k_block(
    const float* __restrict__ x, float* __restrict__ h,
    const bf16* __restrict__ wf1t, const float* __restrict__ bf1,
    const float* __restrict__ g1, const float* __restrict__ be1,
    const bf16* __restrict__ wqt, const float* __restrict__ bq,
    const bf16* __restrict__ wpt, const float* __restrict__ bp,
    const float* __restrict__ g2, const float* __restrict__ be2,
    const bf16* __restrict__ w1t, const float* __restrict__ b1,
    const bf16* __restrict__ w2t, const float* __restrict__ b2,
    const bf16* __restrict__ wf2t, const float* __restrict__ bf2,
    float* __restrict__ out)
{
    __shared__ __align__(16) bf16 bufA[8192];  // xn1 -> q -> attn-out -> u
    __shared__ __align__(16) bf16 bufB[8192];  // k/P -> xn2 -> hfinal(M1)
    __shared__ __align__(16) bf16 bufC[8192];  // xs(M0) / LN partials / vt
    const int tid = threadIdx.x, base = blockIdx.x * 64;
    const int wid = tid >> 6, lrow = tid & 15, lgrp = (tid >> 4) & 3;
    const int cb0 = wid * 32;                  // wave's n-col base (128-dim data)

    f32x4 hraw[2][4];   // h (pre-attn residual): [nt][tt], lane rows cb0+nt*16+lgrp*4+i, token tt*16+lrow

    if (MODE == 0) {
        // ---- ff1 fused: stage x, prefetch ff1 frags, compute hraw = gelu(x@w+b)
        short8 wf1[2][2];
#pragma unroll
        for (int nt = 0; nt < 2; ++nt)
#pragma unroll
            for (int kk = 0; kk < 2; ++kk)
                wf1[nt][kk] = gld8(wf1t + (size_t)(cb0 + nt * 16 + lrow) * 64 + kk * 32 + lgrp * 8);
        {
            int row = tid >> 2, q = tid & 3;
#pragma unroll
            for (int s = 0; s < 2; ++s) {
                int gg = q + s * 4;
                const float4* src = reinterpret_cast<const float4*>(x + (size_t)(base + row) * 64 + gg * 8);
                float4 v0 = src[0], v1 = src[1];
                short8 w;
                w[0] = bfbits(v0.x); w[1] = bfbits(v0.y); w[2] = bfbits(v0.z); w[3] = bfbits(v0.w);
                w[4] = bfbits(v1.x); w[5] = bfbits(v1.y); w[6] = bfbits(v1.z); w[7] = bfbits(v1.w);
                *reinterpret_cast<short8*>(&bufC[row * 64 + ((gg * 8) ^ ((row & 7) << 3))]) = w;
            }
        }
        __syncthreads();
        short8 xb1[4][2];
#pragma unroll
        for (int tt = 0; tt < 4; ++tt)
#pragma unroll
            for (int kk = 0; kk < 2; ++kk)
                xb1[tt][kk] = ldsA64(bufC, tt * 16 + lrow, kk * 32 + lgrp * 8);
        __syncthreads();   // xs reads done; bufC reusable for LN partials
#pragma unroll
        for (int nt = 0; nt < 2; ++nt) {
            float4 bv = *reinterpret_cast<const float4*>(bf1 + cb0 + nt * 16 + lgrp * 4);
#pragma unroll
            for (int tt = 0; tt < 4; ++tt) {
                f32x4 d = {0.f, 0.f, 0.f, 0.f};
#pragma unroll
                for (int kk = 0; kk < 2; ++kk)
                    d = __builtin_amdgcn_mfma_f32_16x16x32_bf16(wf1[nt][kk], xb1[tt][kk], d, 0, 0, 0);
                f32x4 r;
                r[0] = gelu_f(d[0] + bv.x); r[1] = gelu_f(d[1] + bv.y);
                r[2] = gelu_f(d[2] + bv.z); r[3] = gelu_f(d[3] + bv.w);
                hraw[nt][tt] = r;
            }
        }
    } else {
        // ---- load h once, [n][token] register layout
#pragma unroll
        for (int nt = 0; nt < 2; ++nt)
#pragma unroll
            for (int tt = 0; tt < 4; ++tt) {
                int tok = base + OFFSET + tt * 16 + lrow; if (tok >= NPIX) tok -= NPIX;
                float4 hv = *reinterpret_cast<const float4*>(h + (size_t)tok * 128 + cb0 + nt * 16 + lgrp * 4);
                f32x4 r; r[0] = hv.x; r[1] = hv.y; r[2] = hv.z; r[3] = hv.w;
                hraw[nt][tt] = r;
            }
        __syncthreads();   // (uniform barrier structure)
    }

    // ---- LN1 (cross-wave over n) -> xn1 in bufA
    float2* ws = reinterpret_cast<float2*>(bufC);
#pragma unroll
    for (int tt = 0; tt < 4; ++tt) {
        float s = 0.f, q = 0.f;
#pragma unroll
        for (int nt = 0; nt < 2; ++nt)
#pragma unroll
            for (int i = 0; i < 4; ++i) { float v = hraw[nt][tt][i]; s += v; q += v * v; }
        s += __shfl_xor(s, 16, 64); s += __shfl_xor(s, 32, 64);
        q += __shfl_xor(q, 16, 64); q += __shfl_xor(q, 32, 64);
        if (lgrp == 0) { float2 t2; t2.x = s; t2.y = q; ws[wid * 64 + tt * 16 + lrow] = t2; }
    }
    __syncthreads();
    {
        float mu[4], rstd[4];
#pragma unroll
        for (int tt = 0; tt < 4; ++tt) {
            float s = 0.f, q = 0.f;
#pragma unroll
            for (int w = 0; w < 4; ++w) {
                float2 t2 = ws[w * 64 + tt * 16 + lrow];
                s += t2.x; q += t2.y;
            }
            float m = s * (1.f / 128.f);
            mu[tt] = m;
            rstd[tt] = rsqrtf(q * (1.f / 128.f) - m * m + 1e-5f);
        }
        float4 gv[2], bev[2];
#pragma unroll
        for (int nt = 0; nt < 2; ++nt) {
            gv[nt]  = *reinterpret_cast<const float4*>(g1 + cb0 + nt * 16 + lgrp * 4);
            bev[nt] = *reinterpret_cast<const float4*>(be1 + cb0 + nt * 16 + lgrp * 4);
        }
#pragma unroll
        for (int nt = 0; nt < 2; ++nt)
#pragma unroll
            for (int tt = 0; tt < 4; ++tt) {
                short4v pk;
                pk[0] = bfbits((hraw[nt][tt][0] - mu[tt]) * rstd[tt] * gv[nt].x + bev[nt].x);
                pk[1] = bfbits((hraw[nt][tt][1] - mu[tt]) * rstd[tt] * gv[nt].y + bev[nt].y);
                pk[2] = bfbits((hraw[nt][tt][2] - mu[tt]) * rstd[tt] * gv[nt].z + bev[nt].z);
                pk[3] = bfbits((hraw[nt][tt][3] - mu[tt]) * rstd[tt] * gv[nt].w + bev[nt].w);
                int row = tt * 16 + lrow;
                int c = cb0 + nt * 16 + lgrp * 4;
                *reinterpret_cast<short4v*>(&bufA[row * 128 + (c ^ ((row & 7) << 3))]) = pk;
            }
    }

    // prefetch qkv weight group 0 (nt 0,1) — consumed after two barriers
    const int qc = wid * 96;
    short8 wq0[2][4], wq1[2][4];
#pragma unroll
    for (int j = 0; j < 2; ++j)
#pragma unroll
        for (int kk = 0; kk < 4; ++kk)
            wq0[j][kk] = gld8(wqt + (size_t)(qc + j * 16 + lrow) * 128 + kk * 32 + lgrp * 8);
    __syncthreads();

    short8 xb[4][4];
#pragma unroll
    for (int tt = 0; tt < 4; ++tt)
#pragma unroll
        for (int kk = 0; kk < 4; ++kk)
            xb[tt][kk] = ldsA(bufA, tt * 16 + lrow, kk * 32 + lgrp * 8);
    __syncthreads();   // xn1 reads done before q overwrites bufA

    // ---- qkv: 3 rolling groups of 2 n-tiles
#define QKV_TILE(WF, NB)                                                            \
    {                                                                               \
        const int cb = qc + (NB) * 16;                                              \
        float4 bqv = *reinterpret_cast<const float4*>(bq + cb + lgrp * 4);          \
        _Pragma("unroll")                                                           \
        for (int tt = 0; tt < 4; ++tt) {                                            \
            f32x4 d = {0.f, 0.f, 0.f, 0.f};                                         \
            _Pragma("unroll")                                                       \
            for (int kk = 0; kk < 4; ++kk)                                          \
                d = __builtin_amdgcn_mfma_f32_16x16x32_bf16(WF[kk], xb[tt][kk], d, 0, 0, 0); \
            int row = tt * 16 + lrow;                                               \
            if (cb < 128) {                                                         \
                int c = cb + lgrp * 4;                                              \
                short4v pk;                                                         \
                pk[0] = bfbits((d[0] + bqv.x) * SCALE_Q); pk[1] = bfbits((d[1] + bqv.y) * SCALE_Q); \
                pk[2] = bfbits((d[2] + bqv.z) * SCALE_Q); pk[3] = bfbits((d[3] + bqv.w) * SCALE_Q); \
                *reinterpret_cast<short4v*>(&bufA[row * 128 + (c ^ ((row & 7) << 3))]) = pk; \
            } else if (cb < 256) {                                                  \
                int c = cb - 128 + lgrp * 4;                                        \
                short4v pk;                                                         \
                pk[0] = bfbits(d[0] + bqv.x); pk[1] = bfbits(d[1] + bqv.y);         \
                pk[2] = bfbits(d[2] + bqv.z); pk[3] = bfbits(d[3] + bqv.w);         \
                *reinterpret_cast<short4v*>(&bufB[row * 128 + (c ^ ((row & 7) << 3))]) = pk; \
            } else {                                                                \
                int db = cb - 256 + lgrp * 4;                                       \
                bufC[tt * 2048 + (db + 0) * 16 + lrow] = __float2bfloat16(d[0] + bqv.x); \
                bufC[tt * 2048 + (db + 1) * 16 + lrow] = __float2bfloat16(d[1] + bqv.y); \
                bufC[tt * 2048 + (db + 2) * 16 + lrow] = __float2bfloat16(d[2] + bqv.z); \
                bufC[tt * 2048 + (db + 3) * 16 + lrow] = __float2bfloat16(d[3] + bqv.w); \
            }                                                                       \
        }                                                                           \
    }

#pragma unroll
    for (int j = 0; j < 2; ++j)
#pragma unroll
        for (int kk = 0; kk < 4; ++kk)
            wq1[j][kk] = gld8(wqt + (size_t)(qc + (j + 2) * 16 + lrow) * 128 + kk * 32 + lgrp * 8);
    QKV_TILE(wq0[0], 0) QKV_TILE(wq0[1], 1)
#pragma unroll
    for (int j = 0; j < 2; ++j)
#pragma unroll
        for (int kk = 0; kk < 4; ++kk)
            wq0[j][kk] = gld8(wqt + (size_t)(qc + (j + 4) * 16 + lrow) * 128 + kk * 32 + lgrp * 8);
    QKV_TILE(wq1[0], 2) QKV_TILE(wq1[1], 3)
    QKV_TILE(wq0[0], 4) QKV_TILE(wq0[1], 5)
    __syncthreads();

    // ---- prefetch proj frags; scores + softmax + PV
    short8 wfp[2][4];
#pragma unroll
    for (int nt = 0; nt < 2; ++nt)
#pragma unroll
        for (int kk = 0; kk < 4; ++kk)
            wfp[nt][kk] = gld8(wpt + (size_t)(cb0 + nt * 16 + lrow) * 128 + kk * 32 + lgrp * 8);

    float p[4][4];
#pragma unroll
    for (int hh = 0; hh < 4; ++hh) {
        short8 aq = ldsA(bufA, wid * 16 + lrow, hh * 32 + lgrp * 8);
        short8 bk = ldsA(bufB, wid * 16 + lrow, hh * 32 + lgrp * 8);
        f32x4 z = {0.f, 0.f, 0.f, 0.f};
        f32x4 s = __builtin_amdgcn_mfma_f32_16x16x32_bf16(aq, bk, z, 0, 0, 0);
#pragma unroll
        for (int i = 0; i < 4; ++i) {
            float m_ = s[i];
            m_ = fmaxf(m_, __shfl_xor(m_, 1, 64));
            m_ = fmaxf(m_, __shfl_xor(m_, 2, 64));
            m_ = fmaxf(m_, __shfl_xor(m_, 4, 64));
            m_ = fmaxf(m_, __shfl_xor(m_, 8, 64));
            float e = __expf(s[i] - m_);
            float sum = e;
            sum += __shfl_xor(sum, 1, 64);
            sum += __shfl_xor(sum, 2, 64);
            sum += __shfl_xor(sum, 4, 64);
            sum += __shfl_xor(sum, 8, 64);
            p[hh][i] = e * __builtin_amdgcn_rcpf(sum);
        }
    }
    bf16* pl = bufB + wid * 2048;
#pragma unroll
    for (int hh = 0; hh < 4; ++hh)
#pragma unroll
        for (int i = 0; i < 4; ++i)
            pl[hh * 256 + (lgrp * 4 + i) * 16 + lrow] = __float2bfloat16(p[hh][i]);

    short8 z8 = {0, 0, 0, 0, 0, 0, 0, 0};
#pragma unroll
    for (int dt = 0; dt < 8; ++dt) {
        int hh = dt >> 1;
        short8 av = z8, bv = z8;
        if (lgrp < 2) {
            av = *reinterpret_cast<const short8*>(&bufC[wid * 2048 + (dt * 16 + lrow) * 16 + lgrp * 8]);
            bv = *reinterpret_cast<const short8*>(&pl[hh * 256 + lrow * 16 + lgrp * 8]);
        }
        f32x4 z = {0.f, 0.f, 0.f, 0.f};
        f32x4 o = __builtin_amdgcn_mfma_f32_16x16x32_bf16(av, bv, z, 0, 0, 0);
        int row = wid * 16 + lrow;
        int c = dt * 16 + lgrp * 4;
        short4v pk;
        pk[0] = bfbits(o[0]); pk[1] = bfbits(o[1]); pk[2] = bfbits(o[2]); pk[3] = bfbits(o[3]);
        *reinterpret_cast<short4v*>(&bufA[row * 128 + (c ^ ((row & 7) << 3))]) = pk;
    }
    __syncthreads();   // attn-out done; vt/P reads done

    // ---- proj + residual (all in regs)
    short8 af[4][4];
#pragma unroll
    for (int tt = 0; tt < 4; ++tt)
#pragma unroll
        for (int kk = 0; kk < 4; ++kk)
            af[tt][kk] = ldsA(bufA, tt * 16 + lrow, kk * 32 + lgrp * 8);
    f32x4 hres[2][4];
#pragma unroll
    for (int nt = 0; nt < 2; ++nt) {
        float4 bpv = *reinterpret_cast<const float4*>(bp + cb0 + nt * 16 + lgrp * 4);
#pragma unroll
        for (int tt = 0; tt < 4; ++tt) {
            f32x4 d = {0.f, 0.f, 0.f, 0.f};
#pragma unroll
            for (int kk = 0; kk < 4; ++kk)
                d = __builtin_amdgcn_mfma_f32_16x16x32_bf16(wfp[nt][kk], af[tt][kk], d, 0, 0, 0);
            f32x4 r = hraw[nt][tt];
            r[0] += bpv.x + d[0]; r[1] += bpv.y + d[1];
            r[2] += bpv.z + d[2]; r[3] += bpv.w + d[3];
            hres[nt][tt] = r;
        }
    }

    // ---- LN2 -> xn2 in bufB
#pragma unroll
    for (int tt = 0; tt < 4; ++tt) {
        float s = 0.f, q = 0.f;
#pragma unroll
        for (int nt = 0; nt < 2; ++nt)
#pragma unroll
            for (int i = 0; i < 4; ++i) { float v = hres[nt][tt][i]; s += v; q += v * v; }
        s += __shfl_xor(s, 16, 64); s += __shfl_xor(s, 32, 64);
        q += __shfl_xor(q, 16, 64); q += __shfl_xor(q, 32, 64);
        if (lgrp == 0) { float2 t2; t2.x = s; t2.y = q; ws[wid * 64 + tt * 16 + lrow] = t2; }
    }
    __syncthreads();
    short8 w1f[2][2][4];
    {
        float mu[4], rstd[4];
#pragma unroll
        for (int tt = 0; tt < 4; ++tt) {
            float s = 0.f, q = 0.f;
#pragma unroll
            for (int w = 0; w < 4; ++w) {
                float2 t2 = ws[w * 64 + tt * 16 + lrow];
                s += t2.x; q += t2.y;
            }
            float m = s * (1.f / 128.f);
            mu[tt] = m;
            rstd[tt] = rsqrtf(q * (1.f / 128.f) - m * m + 1e-5f);
        }
        float4 gv[2], bev[2];
#pragma unroll
        for (int nt = 0; nt < 2; ++nt) {
            gv[nt]  = *reinterpret_cast<const float4*>(g2 + cb0 + nt * 16 + lgrp * 4);
            bev[nt] = *reinterpret_cast<const float4*>(be2 + cb0 + nt * 16 + lgrp * 4);
        }
#pragma unroll
        for (int nt = 0; nt < 2; ++nt)
#pragma unroll
            for (int tt = 0; tt < 4; ++tt) {
                short4v pk;
                pk[0] = bfbits((hres[nt][tt][0] - mu[tt]) * rstd[tt] * gv[nt].x + bev[nt].x);
                pk[1] = bfbits((hres[nt][tt][1] - mu[tt]) * rstd[tt] * gv[nt].y + bev[nt].y);
                pk[2] = bfbits((hres[nt][tt][2] - mu[tt]) * rstd[tt] * gv[nt].z + bev[nt].z);
                pk[3] = bfbits((hres[nt][tt][3] - mu[tt]) * rstd[tt] * gv[nt].w + bev[nt].w);
                int row = tt * 16 + lrow;
                int c = cb0 + nt * 16 + lgrp * 4;
                *reinterpret_cast<short4v*>(&bufB[row * 128 + (c ^ ((row & 7) << 3))]) = pk;
            }
    }
    // prefetch mlp1 chunk-0 frags (consumed after barrier)
#pragma unroll
    for (int nt = 0; nt < 2; ++nt)
#pragma unroll
        for (int kk = 0; kk < 4; ++kk)
            w1f[0][nt][kk] = gld8(w1t + (size_t)(cb0 + nt * 16 + lrow) * 128 + kk * 32 + lgrp * 8);
    __syncthreads();

    // ---- MLP: 4 chunks of 128, software-pipelined weight loads
    f32x4 acc2[2][4];
#pragma unroll
    for (int nt = 0; nt < 2; ++nt)
#pragma unroll
        for (int tt = 0; tt < 4; ++tt) acc2[nt][tt] = (f32x4){0.f, 0.f, 0.f, 0.f};

#pragma unroll
    for (int ch = 0; ch < 4; ++ch) {
        short8 w2f[2][4];
#pragma unroll
        for (int nt = 0; nt < 2; ++nt)
#pragma unroll
            for (int kk = 0; kk < 4; ++kk)
                w2f[nt][kk] = gld8(w2t + (size_t)(cb0 + nt * 16 + lrow) * 512 + ch * 128 + kk * 32 + lgrp * 8);
        // mlp1: u = gelu(xn2 @ w1 + b1) -> bufA
        float4 b1v[2];
#pragma unroll
        for (int nt = 0; nt < 2; ++nt)
            b1v[nt] = *reinterpret_cast<const float4*>(b1 + ch * 128 + cb0 + nt * 16 + lgrp * 4);
#pragma unroll
        for (int tt = 0; tt < 4; ++tt) {
            short8 xf[4];
#pragma unroll
            for (int kk = 0; kk < 4; ++kk)
                xf[kk] = ldsA(bufB, tt * 16 + lrow, kk * 32 + lgrp * 8);
#pragma unroll
            for (int nt = 0; nt < 2; ++nt) {
                f32x4 d = {0.f, 0.f, 0.f, 0.f};
#pragma unroll
                for (int kk = 0; kk < 4; ++kk)
                    d = __builtin_amdgcn_mfma_f32_16x16x32_bf16(w1f[ch & 1][nt][kk], xf[kk], d, 0, 0, 0);
                short4v pk;
                pk[0] = bfbits(gelu_f(d[0] + b1v[nt].x)); pk[1] = bfbits(gelu_f(d[1] + b1v[nt].y));
                pk[2] = bfbits(gelu_f(d[2] + b1v[nt].z)); pk[3] = bfbits(gelu_f(d[3] + b1v[nt].w));
                int row = tt * 16 + lrow;
                int c = cb0 + nt * 16 + lgrp * 4;
                *reinterpret_cast<short4v*>(&bufA[row * 128 + (c ^ ((row & 7) << 3))]) = pk;
            }
        }
        __syncthreads();
        if (ch < 3) {
#pragma unroll
            for (int nt = 0; nt < 2; ++nt)
#pragma unroll
                for (int kk = 0; kk < 4; ++kk)
                    w1f[(ch + 1) & 1][nt][kk] =
                        gld8(w1t + (size_t)((ch + 1) * 128 + cb0 + nt * 16 + lrow) * 128 + kk * 32 + lgrp * 8);
        }
        // mlp2: acc2 += u @ w2
#pragma unroll
        for (int tt = 0; tt < 4; ++tt) {
            short8 uf[4];
#pragma unroll
            for (int kk = 0; kk < 4; ++kk)
                uf[kk] = ldsA(bufA, tt * 16 + lrow, kk * 32 + lgrp * 8);
#pragma unroll
            for (int nt = 0; nt < 2; ++nt)
#pragma unroll
                for (int kk = 0; kk < 4; ++kk)
                    acc2[nt][tt] = __builtin_amdgcn_mfma_f32_16x16x32_bf16(
                        w2f[nt][kk], uf[kk], acc2[nt][tt], 0, 0, 0);
        }
        __syncthreads();
    }

    if (MODE == 0) {
        // ---- epilogue: h = hres + b2 + acc2
#pragma unroll
        for (int nt = 0; nt < 2; ++nt) {
            const int n0 = cb0 + nt * 16 + lgrp * 4;
            float4 b2v = *reinterpret_cast<const float4*>(b2 + n0);
#pragma unroll
            for (int tt = 0; tt < 4; ++tt) {
                int tok = base + OFFSET + tt * 16 + lrow; if (tok >= NPIX) tok -= NPIX;
                float4 ov;
                ov.x = hres[nt][tt][0] + b2v.x + acc2[nt][tt][0];
                ov.y = hres[nt][tt][1] + b2v.y + acc2[nt][tt][1];
                ov.z = hres[nt][tt][2] + b2v.z + acc2[nt][tt][2];
                ov.w = hres[nt][tt][3] + b2v.w + acc2[nt][tt][3];
                *reinterpret_cast<float4*>(h + (size_t)tok * 128 + n0) = ov;
            }
        }
    } else {
        // ---- epilogue: out = x + (hfinal) @ wff2 + bff2 (ff2 fused)
        short8 wff[4];
#pragma unroll
        for (int kk = 0; kk < 4; ++kk)
            wff[kk] = gld8(wf2t + (size_t)(wid * 16 + lrow) * 128 + kk * 32 + lgrp * 8);
        float4 xv[4];
#pragma unroll
        for (int tt = 0; tt < 4; ++tt) {
            int tok = base + OFFSET + tt * 16 + lrow; if (tok >= NPIX) tok -= NPIX;
            xv[tt] = *reinterpret_cast<const float4*>(x + (size_t)tok * 64 + wid * 16 + lgrp * 4);
        }
#pragma unroll
        for (int nt = 0; nt < 2; ++nt) {
            const int n0 = cb0 + nt * 16 + lgrp * 4;
            float4 b2v = *reinterpret_cast<const float4*>(b2 + n0);
#pragma unroll
            for (int tt = 0; tt < 4; ++tt) {
                short4v pk;
                pk[0] = bfbits(hres[nt][tt][0] + b2v.x + acc2[nt][tt][0]);
                pk[1] = bfbits(hres[nt][tt][1] + b2v.y + acc2[nt][tt][1]);
                pk[2] = bfbits(hres[nt][tt][2] + b2v.z + acc2[nt][tt][2]);
                pk[3] = bfbits(hres[nt][tt][3] + b2v.w + acc2[nt][tt][3]);
                int row = tt * 16 + lrow;
                int c = cb0 + nt * 16 + lgrp * 4;
                *reinterpret_cast<short4v*>(&bufB[row * 128 + (c ^ ((row & 7) << 3))]) = pk;
            }
        }
        __syncthreads();
        float4 bfv = *reinterpret_cast<const float4*>(bf2 + wid * 16 + lgrp * 4);
#pragma unroll
        for (int tt = 0; tt < 4; ++tt) {
            short8 bfr[4];
#pragma unroll
            for (int kk = 0; kk < 4; ++kk)
                bfr[kk] = ldsA(bufB, tt * 16 + lrow, kk * 32 + lgrp * 8);
            f32x4 d = {0.f, 0.f, 0.f, 0.f};
#pragma unroll
            for (int kk = 0; kk < 4; ++kk)
                d = __builtin_amdgcn_mfma_f32_16x16x32_bf16(wff[kk], bfr[kk], d, 0, 0, 0);
            int tok = base + OFFSET + tt * 16 + lrow; if (tok >= NPIX) tok -= NPIX;
            float4 ov;
            ov.x = xv[tt].x + bfv.x + d[0]; ov.y = xv[tt].y + bfv.y + d[1];
            ov.z = xv[tt].z + bfv.z + d[2]; ov.w = xv[tt].w + bfv.w + d[3];
            *reinterpret_cast<float4*>(out + (size_t)tok * 64 + wid * 16 + lgrp * 4) = ov;
        }
    }
#undef QKV_TILE
}

extern "C" void kernel_launch(void* const* d_in, const int* in_sizes, int n_in,
                              void* d_out, int out_size, void* d_ws, size_t ws_size,
                              hipStream_t stream) {
    (void)in_sizes; (void)n_in; (void)out_size; (void)ws_size;
    const float* x      = (const float*)d_in[0];
    const float* w_ff1  = (const float*)d_in[1];
    const float* b_ff1  = (const float*)d_in[2];
    const float* ln1_g  = (const float*)d_in[3];
    const float* ln1_b  = (const float*)d_in[4];
    const float* w_qkv  = (const float*)d_in[5];
    const float* b_qkv  = (const float*)d_in[6];
    const float* w_proj = (const float*)d_in[7];
    const float* b_proj = (const float*)d_in[8];
    const float* ln2_g  = (const float*)d_in[9];
    const float* ln2_b  = (const float*)d_in[10];
    const float* w_mlp1 = (const float*)d_in[11];
    const float* b_mlp1 = (const float*)d_in[12];
    const float* w_mlp2 = (const float*)d_in[13];
    const float* b_mlp2 = (const float*)d_in[14];
    const float* w_ff2  = (const float*)d_in[15];
    const float* b_ff2  = (const float*)d_in[16];
    float* out = (float*)d_out;

    float* h = (float*)d_ws;                                   // [NPIX,128] fp32
    bf16* wbf = (bf16*)((char*)d_ws + (size_t)NPIX * 128 * 4);
    bf16* ff1t  = wbf;            // [128][64]
    bf16* qkvt  = wbf + 8192;     // 2x[384][128]
    bf16* projt = wbf + 106496;   // 2x[128][128]
    bf16* mlp1t = wbf + 139264;   // 2x[512][128]
    bf16* mlp2t = wbf + 270336;   // 2x[128][512]
    bf16* ff2t  = wbf + 401408;   // [64][128]

    dim3 blk(256);
    k_convert<<<1600, blk, 0, stream>>>(w_ff1, w_qkv, w_proj, w_mlp1, w_mlp2, w_ff2, wbf);

    const int NB = NPIX / 64;  // 3072
    k_block<0, 0><<<NB, blk, 0, stream>>>(x, h,
        ff1t, b_ff1,
        ln1_g, ln1_b, qkvt, b_qkv, projt, b_proj,
        ln2_g, ln2_b, mlp1t, b_mlp1, mlp2t, b_mlp2,
        ff2t, b_ff2, out);

    k_block<8, 1><<<NB, blk, 0, stream>>>(x, h,
        ff1t, b_ff1,
        ln1_g + 128, ln1_b + 128, qkvt + 49152, b_qkv + 384, projt + 16384, b_proj + 128,
        ln2_g + 128, ln2_b + 128, mlp1t + 65536, b_mlp1 + 512, mlp2t + 65536, b_mlp2 + 128,
        ff2t, b_ff2, out);
}